// Round 9
// baseline (800.341 us; speedup 1.0000x reference)
//
#include <hip/hip_runtime.h>

// GCN 2-layer + mean-pool + linear head, f32.
// Round 9: agg traffic is structural (per-XCD L2 footprint 51MB >> 4MB).
//   - agg_sliced: feature-slice (16 cols = 1 line) aligned to XCDs via
//     blockIdx%SL, + 2-pass src-range split -> per-XCD-per-pass working
//     set 3.2MB < 4MB L2. Register accumulators across passes.
//   - all nontemporal ops reverted (round-8 regression).
// GEMMs (fragment-packed MFMA split-bf16, dis-prescale epilogue), scan,
// CSR build, pool unchanged.

#define NN 100000
#define NG 128
#define SCHUNK 1024

typedef __attribute__((ext_vector_type(8))) short short8;
typedef __attribute__((ext_vector_type(4))) float f32x4;

__device__ __forceinline__ unsigned short f2bf(float f) {
    union { float f; unsigned u; } v; v.f = f;
    unsigned r = v.u + 0x7fffu + ((v.u >> 16) & 1u);  // round-nearest-even
    return (unsigned short)(r >> 16);
}
__device__ __forceinline__ float bf2f(unsigned short h) {
    union { unsigned u; float f; } v; v.u = ((unsigned)h) << 16;
    return v.f;
}

__global__ __launch_bounds__(256) void deg_kernel(const int* __restrict__ dst,
                                                  int* __restrict__ deg, int E) {
    int i = blockIdx.x * blockDim.x + threadIdx.x;
    int stride = gridDim.x * blockDim.x;
    for (; i < E; i += stride) atomicAdd(&deg[dst[i]], 1);
}

// ---- 3-kernel exclusive scan of deg -> rowptr, fused dis = rsqrt(deg+1) ----
__global__ __launch_bounds__(256) void scan_part(const int* __restrict__ deg,
                                                 int* __restrict__ bsum, int N) {
    const int t = threadIdx.x;
    const int i = blockIdx.x * SCHUNK + t * 4;
    int4 v = make_int4(0, 0, 0, 0);
    if (i + 3 < N) v = *(const int4*)(deg + i);
    else {
        if (i < N) v.x = deg[i];
        if (i + 1 < N) v.y = deg[i + 1];
        if (i + 2 < N) v.z = deg[i + 2];
    }
    int s = v.x + v.y + v.z + v.w;
#pragma unroll
    for (int d = 1; d < 64; d <<= 1) s += __shfl_xor(s, d);
    __shared__ int ws[4];
    if ((t & 63) == 0) ws[t >> 6] = s;
    __syncthreads();
    if (t == 0) bsum[blockIdx.x] = ws[0] + ws[1] + ws[2] + ws[3];
}

__global__ __launch_bounds__(128) void scan_top(int* __restrict__ bsum, int NB) {
    __shared__ int sm[128];
    const int t = threadIdx.x;
    const int v = (t < NB) ? bsum[t] : 0;
    sm[t] = v;
    __syncthreads();
    for (int d = 1; d < 128; d <<= 1) {
        int a = (t >= d) ? sm[t - d] : 0;
        __syncthreads();
        sm[t] += a;
        __syncthreads();
    }
    if (t < NB) bsum[t] = sm[t] - v;  // exclusive
}

__global__ __launch_bounds__(256) void scan_write(const int* __restrict__ deg,
                                                  const int* __restrict__ bsum,
                                                  int* __restrict__ rowptr,
                                                  float* __restrict__ dis,
                                                  int N, int NB) {
    const int t = threadIdx.x;
    const int i = blockIdx.x * SCHUNK + t * 4;
    int4 v = make_int4(0, 0, 0, 0);
    if (i + 3 < N) v = *(const int4*)(deg + i);
    else {
        if (i < N) v.x = deg[i];
        if (i + 1 < N) v.y = deg[i + 1];
        if (i + 2 < N) v.z = deg[i + 2];
    }
    const int s = v.x + v.y + v.z + v.w;
    __shared__ int sm[256];
    sm[t] = s;
    __syncthreads();
    for (int d = 1; d < 256; d <<= 1) {
        int a = (t >= d) ? sm[t - d] : 0;
        __syncthreads();
        sm[t] += a;
        __syncthreads();
    }
    int run = bsum[blockIdx.x] + sm[t] - s;
    const int dv[4] = {v.x, v.y, v.z, v.w};
#pragma unroll
    for (int j = 0; j < 4; ++j) {
        if (i + j < N) {
            rowptr[i + j] = run;
            dis[i + j] = rsqrtf((float)dv[j] + 1.0f);
        }
        run += dv[j];
    }
    if (blockIdx.x == NB - 1 && t == 255) rowptr[N] = run;  // == E
}

__global__ __launch_bounds__(256) void csr_fill(const int* __restrict__ src,
                                                const int* __restrict__ dst,
                                                const int* __restrict__ rowptr,
                                                int* __restrict__ fill,
                                                int* __restrict__ col, int E) {
    int i = blockIdx.x * blockDim.x + threadIdx.x;
    int stride = gridDim.x * blockDim.x;
    for (; i < E; i += stride) {
        const int d = dst[i];
        const int pos = rowptr[d] + atomicAdd(&fill[d], 1);
        col[pos] = src[i];
    }
}

// One-time weight pack: W [K][BN] f32 -> hi/lo bf16 in MFMA fragment order.
__global__ __launch_bounds__(256) void pack_w(const float* __restrict__ W,
                                              unsigned short* __restrict__ packH,
                                              unsigned short* __restrict__ packL,
                                              int K, int BN) {
    const int idx = blockIdx.x * blockDim.x + threadIdx.x;
    if (idx >= K * BN) return;
    const int e = idx & 7;
    const int l = (idx >> 3) & 63;
    const int rest = idx >> 9;  // ks*NF + nf
    const int NF = BN >> 4;
    const int nf = rest % NF;
    const int ks = rest / NF;
    const int n = nf * 16 + (l & 15);
    const int k = ks * 32 + ((l >> 4) & 3) * 8 + e;
    const float v = W[(size_t)k * BN + n];
    const unsigned short h = f2bf(v);
    packH[idx] = h;
    packL[idx] = f2bf(v - bf2f(h));
}

// MFMA split-bf16 GEMM: A [N][K] f32 row-major, W pre-packed fragments.
// Epilogue scales each output row by scale[row] (dis pre-scaling for agg).
template <int BN>
__global__ __launch_bounds__(256) void gemm_mfma(const float* __restrict__ A,
                                                 const unsigned short* __restrict__ WpH,
                                                 const unsigned short* __restrict__ WpL,
                                                 const float* __restrict__ scale,
                                                 float* __restrict__ Out,
                                                 int N, int K) {
    constexpr int BM = 128;
    constexpr int WROWS = (BN == 128) ? 2 : 4;
    constexpr int WCOLS = (BN == 128) ? 2 : 1;
    constexpr int WTM = BM / WROWS;
    constexpr int MF = WTM / 16;
    constexpr int NFW = (BN / WCOLS) / 16;
    constexpr int NFB = BN / 16;

    __shared__ unsigned short AsH[8][512];
    __shared__ unsigned short AsL[8][512];

    const int t = threadIdx.x;
    const int wid = t >> 6, lane = t & 63;
    const int wr = wid / WCOLS, wc = wid % WCOLS;
    const int r0 = blockIdx.x * BM;

    const int s_row1 = t >> 2;
    const int s_row2 = (t + 256) >> 2;
    const int s_kg = t & 3;
    const int s_lf = ((t >> 2) & 15) + s_kg * 16;

    f32x4 acc[MF][NFW];
#pragma unroll
    for (int m = 0; m < MF; ++m)
#pragma unroll
        for (int n = 0; n < NFW; ++n) acc[m][n] = (f32x4){0.f, 0.f, 0.f, 0.f};

    for (int k0 = 0; k0 < K; k0 += 32) {
        const int ks = k0 >> 5;
#pragma unroll
        for (int uu = 0; uu < 2; ++uu) {
            const int row = uu ? s_row2 : s_row1;
            const int gr = r0 + row;
            float4 v0 = make_float4(0.f, 0.f, 0.f, 0.f), v1 = v0;
            if (gr < N) {
                const float* ap = &A[(size_t)gr * K + k0 + s_kg * 8];
                v0 = *(const float4*)ap;
                v1 = *(const float4*)(ap + 4);
            }
            short8 h, l;
            const float vv[8] = {v0.x, v0.y, v0.z, v0.w, v1.x, v1.y, v1.z, v1.w};
#pragma unroll
            for (int j = 0; j < 8; ++j) {
                const unsigned short hh = f2bf(vv[j]);
                h[j] = (short)hh;
                l[j] = (short)f2bf(vv[j] - bf2f(hh));
            }
            const int m = row >> 4;
            *(short8*)&AsH[m][s_lf * 8] = h;
            *(short8*)&AsL[m][s_lf * 8] = l;
        }
        __syncthreads();

        short8 bH[NFW], bL[NFW];
#pragma unroll
        for (int n = 0; n < NFW; ++n) {
            const int nfg = wc * NFW + n;
            const int base = ((ks * NFB + nfg) * 64 + lane) * 8;
            bH[n] = *(const short8*)&WpH[base];
            bL[n] = *(const short8*)&WpL[base];
        }
#pragma unroll
        for (int m = 0; m < MF; ++m) {
            const int mf = wr * MF + m;
            const short8 aH = *(const short8*)&AsH[mf][lane * 8];
            const short8 aL = *(const short8*)&AsL[mf][lane * 8];
#pragma unroll
            for (int n = 0; n < NFW; ++n) {
                acc[m][n] = __builtin_amdgcn_mfma_f32_16x16x32_bf16(aH, bH[n], acc[m][n], 0, 0, 0);
                acc[m][n] = __builtin_amdgcn_mfma_f32_16x16x32_bf16(aH, bL[n], acc[m][n], 0, 0, 0);
                acc[m][n] = __builtin_amdgcn_mfma_f32_16x16x32_bf16(aL, bH[n], acc[m][n], 0, 0, 0);
            }
        }
        __syncthreads();
    }

#pragma unroll
    for (int m = 0; m < MF; ++m) {
        const int row0 = r0 + wr * WTM + m * 16 + ((lane >> 4) << 2);
        float sc[4];
#pragma unroll
        for (int r = 0; r < 4; ++r) sc[r] = (row0 + r < N) ? scale[row0 + r] : 0.f;
#pragma unroll
        for (int n = 0; n < NFW; ++n) {
            const int cn = wc * (NFW * 16) + n * 16 + (lane & 15);
#pragma unroll
            for (int r = 0; r < 4; ++r) {
                if (row0 + r < N)
                    Out[(size_t)(row0 + r) * BN + cn] = acc[m][n][r] * sc[r];
            }
        }
    }
}

// Feature-sliced CSR gather aggregation over PRE-SCALED H' (= dis*h).
// slice = blockIdx % SL (16 cols = one 64B line) -> aligns to XCDs under
// round-robin dispatch; SPLIT passes over src ranges keep the per-XCD
// per-pass gather footprint < 4MB L2. Out-of-range edges read the node's
// own (hot) line with weight 0 (branchless).
// Out[d] = relu( dis[d] * (sum_s H'[s] + H'[d]) + bias )
template <int COLS, int SPLIT>
__global__ __launch_bounds__(256) void agg_sliced(const int* __restrict__ rowptr,
                                                  const int* __restrict__ col,
                                                  const float* __restrict__ dis,
                                                  const float* __restrict__ Hs,
                                                  const float* __restrict__ bias,
                                                  float* __restrict__ Out, int N) {
    constexpr int SL = COLS / 16;  // slices
    const int slice = (int)blockIdx.x % SL;
    const int nb = (int)blockIdx.x / SL;
    const int t = threadIdx.x;
    const int lane = t & 63, wid = t >> 6;
    const int sub = lane >> 4;      // node within wave (0..3)
    const int sl = lane & 15;       // col within slice
    const int lbase = sub * 16;
    const int node = nb * 16 + wid * 4 + sub;
    const int cb = slice * 16;

    int base = 0, len = 0;
    if (node < N) {
        base = rowptr[node];
        len = rowptr[node + 1] - base;
    }

    float acc = 0.f;
    const int NH = (N + SPLIT - 1) / SPLIT;
    for (int pass = 0; pass < SPLIT; ++pass) {
        const int lo = pass * NH;
        const int hi = lo + NH;
        for (int j0 = 0; j0 < len; j0 += 16) {
            const int remain = min(16, len - j0);
            const int sidx = (sl < remain) ? col[base + j0 + sl] : 0;
            int j = 0;
            for (; j + 16 <= remain; j += 16) {
                float hv[16], ww[16];
#pragma unroll
                for (int u = 0; u < 16; ++u) {
                    int s = __shfl(sidx, lbase + j + u);
                    const bool use = (s >= lo) && (s < hi);
                    ww[u] = use ? 1.f : 0.f;
                    s = use ? s : node;
                    hv[u] = Hs[(size_t)s * COLS + cb + sl];
                }
#pragma unroll
                for (int u = 0; u < 16; ++u) acc = fmaf(hv[u], ww[u], acc);
            }
            for (; j + 8 <= remain; j += 8) {
                float hv[8], ww[8];
#pragma unroll
                for (int u = 0; u < 8; ++u) {
                    int s = __shfl(sidx, lbase + j + u);
                    const bool use = (s >= lo) && (s < hi);
                    ww[u] = use ? 1.f : 0.f;
                    s = use ? s : node;
                    hv[u] = Hs[(size_t)s * COLS + cb + sl];
                }
#pragma unroll
                for (int u = 0; u < 8; ++u) acc = fmaf(hv[u], ww[u], acc);
            }
            for (; j < remain; ++j) {
                int s = __shfl(sidx, lbase + j);
                const bool use = (s >= lo) && (s < hi);
                const float w = use ? 1.f : 0.f;
                s = use ? s : node;
                acc = fmaf(Hs[(size_t)s * COLS + cb + sl], w, acc);
            }
        }
    }

    if (node < N) {
        const float dd = dis[node];
        const float hs = Hs[(size_t)node * COLS + cb + sl];
        const float bv = bias[cb + sl];
        Out[(size_t)node * COLS + cb + sl] = fmaxf(fmaf(acc + hs, dd, bv), 0.f);
    }
}

// mean-pool prep: wave = 32 consecutive rows, lane = column.
__global__ __launch_bounds__(256) void pool_kernel(const float* __restrict__ H,
                                                   const int* __restrict__ batch,
                                                   float* __restrict__ pooled,
                                                   float* __restrict__ cnt, int N) {
    const int c = threadIdx.x & 63;
    const int w = threadIdx.x >> 6;          // wave 0..3
    const int row0 = blockIdx.x * 128 + w * 32;
    if (row0 >= N) return;
    const int nr = min(32, N - row0);

    float v[32];
    int b[32];
#pragma unroll
    for (int i = 0; i < 32; ++i) {
        const int r = row0 + i;
        if (i < nr) {
            v[i] = H[(size_t)r * 64 + c];
            b[i] = batch[r];
        } else {
            v[i] = 0.f;
            b[i] = -1;
        }
    }
    int cur = b[0];
    float sum = 0.f, csum = 0.f;
#pragma unroll
    for (int i = 0; i < 32; ++i) {
        if (i < nr) {
            if (b[i] != cur) {
                atomicAdd(&pooled[cur * 64 + c], sum);
                if (c == 0) atomicAdd(&cnt[cur], csum);
                cur = b[i];
                sum = 0.f;
                csum = 0.f;
            }
            sum += v[i];
            csum += 1.f;
        }
    }
    atomicAdd(&pooled[cur * 64 + c], sum);
    if (c == 0) atomicAdd(&cnt[cur], csum);
}

__global__ __launch_bounds__(256) void final_kernel(const float* __restrict__ pooled,
                                                    const float* __restrict__ cnt,
                                                    const float* __restrict__ Wlin,
                                                    const float* __restrict__ blin,
                                                    float* __restrict__ out) {
    const int t = threadIdx.x;
    const int g = t >> 1, o = t & 1;
    const float inv = 1.0f / fmaxf(cnt[g], 1.0f);
    float s = 0.f;
#pragma unroll
    for (int j = 0; j < 64; ++j) s = fmaf(pooled[g * 64 + j], Wlin[j * 2 + o], s);
    out[t] = s * inv + blin[o];
}

extern "C" void kernel_launch(void* const* d_in, const int* in_sizes, int n_in,
                              void* d_out, int out_size, void* d_ws, size_t ws_size,
                              hipStream_t stream) {
    const float* x     = (const float*)d_in[0];
    const int*   edge  = (const int*)d_in[1];
    const int*   batch = (const int*)d_in[2];
    const float* W1    = (const float*)d_in[3];
    const float* b1    = (const float*)d_in[4];
    const float* W2    = (const float*)d_in[5];
    const float* b2    = (const float*)d_in[6];
    const float* Wlin  = (const float*)d_in[7];
    const float* blin  = (const float*)d_in[8];
    float* out = (float*)d_out;

    const int N = NN;
    const int E = in_sizes[1] / 2;
    const int* src = edge;
    const int* dst = edge + E;
    const int NB = (N + SCHUNK - 1) / SCHUNK;  // 98

    char* ws = (char*)d_ws;
    size_t off = 0;
    auto alloc = [&](size_t bytes) -> void* {
        void* p = ws + off;
        off += (bytes + 511) & ~(size_t)511;
        return p;
    };
    int*   deg    = (int*)alloc((size_t)N * 4);
    float* dis    = (float*)alloc((size_t)N * 4);
    int*   rowptr = (int*)alloc((size_t)(N + 1) * 4);
    int*   fill   = (int*)alloc((size_t)N * 4);
    int*   bsum   = (int*)alloc((size_t)NB * 4);
    int*   col    = (int*)alloc((size_t)E * 4);
    unsigned short* w1h = (unsigned short*)alloc((size_t)384 * 128 * 2);
    unsigned short* w1l = (unsigned short*)alloc((size_t)384 * 128 * 2);
    unsigned short* w2h = (unsigned short*)alloc((size_t)128 * 64 * 2);
    unsigned short* w2l = (unsigned short*)alloc((size_t)128 * 64 * 2);
    float* h1     = (float*)alloc((size_t)N * 128 * 4);
    float* agg1   = (float*)alloc((size_t)N * 128 * 4);
    float* pooled = (float*)alloc((size_t)NG * 64 * 4);
    float* cnt    = (float*)alloc((size_t)NG * 4);
    float* h2   = h1;
    float* agg2 = (float*)((char*)h1 + (size_t)N * 64 * 4);

    hipMemsetAsync(deg, 0, (size_t)N * 4, stream);
    hipMemsetAsync(fill, 0, (size_t)N * 4, stream);
    hipMemsetAsync(pooled, 0, (size_t)NG * 64 * 4, stream);
    hipMemsetAsync(cnt, 0, (size_t)NG * 4, stream);

    // weight packing (tiny, once per call)
    pack_w<<<(384 * 128 + 255) / 256, 256, 0, stream>>>(W1, w1h, w1l, 384, 128);
    pack_w<<<(128 * 64 + 255) / 256, 256, 0, stream>>>(W2, w2h, w2l, 128, 64);

    // degree + CSR build + normalization
    deg_kernel<<<2048, 256, 0, stream>>>(dst, deg, E);
    scan_part<<<NB, 256, 0, stream>>>(deg, bsum, N);
    scan_top<<<1, 128, 0, stream>>>(bsum, NB);
    scan_write<<<NB, 256, 0, stream>>>(deg, bsum, rowptr, dis, N, NB);
    csr_fill<<<2048, 256, 0, stream>>>(src, dst, rowptr, fill, col, E);

    const int gblocks = (N + 127) / 128;
    const int nblk16 = (N + 15) / 16;  // node blocks of 16
    // layer 1 (gemm writes dis-prescaled h1')
    gemm_mfma<128><<<gblocks, 256, 0, stream>>>(x, w1h, w1l, dis, h1, N, 384);
    agg_sliced<128, 2><<<nblk16 * 8, 256, 0, stream>>>(rowptr, col, dis, h1, b1, agg1, N);

    // layer 2 (h2' = dis * (agg1 @ W2), into h1's region)
    gemm_mfma<64><<<gblocks, 256, 0, stream>>>(agg1, w2h, w2l, dis, h2, N, 128);
    agg_sliced<64, 2><<<nblk16 * 4, 256, 0, stream>>>(rowptr, col, dis, h2, b2, agg2, N);

    // pool + head
    pool_kernel<<<(N + 127) / 128, 256, 0, stream>>>(agg2, batch, pooled, cnt, N);
    final_kernel<<<1, 256, 0, stream>>>(pooled, cnt, Wlin, blin, out);
}

// Round 11
// 490.917 us; speedup vs baseline: 1.6303x; 1.6303x over previous
//
#include <hip/hip_runtime.h>

// GCN 2-layer + mean-pool + linear head, f32.
// Round 11: fix round-10 shfl-from-inactive-lane bug in agg_gather.
//   Both edge-subgroups now run UNIFORM trip counts (half = (remain+1)/2);
//   esub1's possibly-invalid last element is masked by VALUE (weight 0,
//   safe row = node) instead of by control flow, so every __shfl source
//   lane is active. float4/lane gathers, 2 subgroups -> 16 rows in flight.
// GEMMs (fragment-packed MFMA split-bf16 + dis-prescale epilogue), scan,
// CSR build, pool unchanged.

#define NN 100000
#define NG 128
#define SCHUNK 1024

typedef __attribute__((ext_vector_type(8))) short short8;
typedef __attribute__((ext_vector_type(4))) float f32x4;

__device__ __forceinline__ unsigned short f2bf(float f) {
    union { float f; unsigned u; } v; v.f = f;
    unsigned r = v.u + 0x7fffu + ((v.u >> 16) & 1u);  // round-nearest-even
    return (unsigned short)(r >> 16);
}
__device__ __forceinline__ float bf2f(unsigned short h) {
    union { unsigned u; float f; } v; v.u = ((unsigned)h) << 16;
    return v.f;
}

__global__ __launch_bounds__(256) void deg_kernel(const int* __restrict__ dst,
                                                  int* __restrict__ deg, int E) {
    int i = blockIdx.x * blockDim.x + threadIdx.x;
    int stride = gridDim.x * blockDim.x;
    for (; i < E; i += stride) atomicAdd(&deg[dst[i]], 1);
}

// ---- 3-kernel exclusive scan of deg -> rowptr, fused dis = rsqrt(deg+1) ----
__global__ __launch_bounds__(256) void scan_part(const int* __restrict__ deg,
                                                 int* __restrict__ bsum, int N) {
    const int t = threadIdx.x;
    const int i = blockIdx.x * SCHUNK + t * 4;
    int4 v = make_int4(0, 0, 0, 0);
    if (i + 3 < N) v = *(const int4*)(deg + i);
    else {
        if (i < N) v.x = deg[i];
        if (i + 1 < N) v.y = deg[i + 1];
        if (i + 2 < N) v.z = deg[i + 2];
    }
    int s = v.x + v.y + v.z + v.w;
#pragma unroll
    for (int d = 1; d < 64; d <<= 1) s += __shfl_xor(s, d);
    __shared__ int ws[4];
    if ((t & 63) == 0) ws[t >> 6] = s;
    __syncthreads();
    if (t == 0) bsum[blockIdx.x] = ws[0] + ws[1] + ws[2] + ws[3];
}

__global__ __launch_bounds__(128) void scan_top(int* __restrict__ bsum, int NB) {
    __shared__ int sm[128];
    const int t = threadIdx.x;
    const int v = (t < NB) ? bsum[t] : 0;
    sm[t] = v;
    __syncthreads();
    for (int d = 1; d < 128; d <<= 1) {
        int a = (t >= d) ? sm[t - d] : 0;
        __syncthreads();
        sm[t] += a;
        __syncthreads();
    }
    if (t < NB) bsum[t] = sm[t] - v;  // exclusive
}

__global__ __launch_bounds__(256) void scan_write(const int* __restrict__ deg,
                                                  const int* __restrict__ bsum,
                                                  int* __restrict__ rowptr,
                                                  float* __restrict__ dis,
                                                  int N, int NB) {
    const int t = threadIdx.x;
    const int i = blockIdx.x * SCHUNK + t * 4;
    int4 v = make_int4(0, 0, 0, 0);
    if (i + 3 < N) v = *(const int4*)(deg + i);
    else {
        if (i < N) v.x = deg[i];
        if (i + 1 < N) v.y = deg[i + 1];
        if (i + 2 < N) v.z = deg[i + 2];
    }
    const int s = v.x + v.y + v.z + v.w;
    __shared__ int sm[256];
    sm[t] = s;
    __syncthreads();
    for (int d = 1; d < 256; d <<= 1) {
        int a = (t >= d) ? sm[t - d] : 0;
        __syncthreads();
        sm[t] += a;
        __syncthreads();
    }
    int run = bsum[blockIdx.x] + sm[t] - s;
    const int dv[4] = {v.x, v.y, v.z, v.w};
#pragma unroll
    for (int j = 0; j < 4; ++j) {
        if (i + j < N) {
            rowptr[i + j] = run;
            dis[i + j] = rsqrtf((float)dv[j] + 1.0f);
        }
        run += dv[j];
    }
    if (blockIdx.x == NB - 1 && t == 255) rowptr[N] = run;  // == E
}

__global__ __launch_bounds__(256) void csr_fill(const int* __restrict__ src,
                                                const int* __restrict__ dst,
                                                const int* __restrict__ rowptr,
                                                int* __restrict__ fill,
                                                int* __restrict__ col, int E) {
    int i = blockIdx.x * blockDim.x + threadIdx.x;
    int stride = gridDim.x * blockDim.x;
    for (; i < E; i += stride) {
        const int d = dst[i];
        const int pos = rowptr[d] + atomicAdd(&fill[d], 1);
        col[pos] = src[i];
    }
}

// One-time weight pack: W [K][BN] f32 -> hi/lo bf16 in MFMA fragment order.
__global__ __launch_bounds__(256) void pack_w(const float* __restrict__ W,
                                              unsigned short* __restrict__ packH,
                                              unsigned short* __restrict__ packL,
                                              int K, int BN) {
    const int idx = blockIdx.x * blockDim.x + threadIdx.x;
    if (idx >= K * BN) return;
    const int e = idx & 7;
    const int l = (idx >> 3) & 63;
    const int rest = idx >> 9;  // ks*NF + nf
    const int NF = BN >> 4;
    const int nf = rest % NF;
    const int ks = rest / NF;
    const int n = nf * 16 + (l & 15);
    const int k = ks * 32 + ((l >> 4) & 3) * 8 + e;
    const float v = W[(size_t)k * BN + n];
    const unsigned short h = f2bf(v);
    packH[idx] = h;
    packL[idx] = f2bf(v - bf2f(h));
}

// MFMA split-bf16 GEMM: A [N][K] f32 row-major, W pre-packed fragments.
// Epilogue scales each output row by scale[row] (dis pre-scaling for agg).
template <int BN>
__global__ __launch_bounds__(256) void gemm_mfma(const float* __restrict__ A,
                                                 const unsigned short* __restrict__ WpH,
                                                 const unsigned short* __restrict__ WpL,
                                                 const float* __restrict__ scale,
                                                 float* __restrict__ Out,
                                                 int N, int K) {
    constexpr int BM = 128;
    constexpr int WROWS = (BN == 128) ? 2 : 4;
    constexpr int WCOLS = (BN == 128) ? 2 : 1;
    constexpr int WTM = BM / WROWS;
    constexpr int MF = WTM / 16;
    constexpr int NFW = (BN / WCOLS) / 16;
    constexpr int NFB = BN / 16;

    __shared__ unsigned short AsH[8][512];
    __shared__ unsigned short AsL[8][512];

    const int t = threadIdx.x;
    const int wid = t >> 6, lane = t & 63;
    const int wr = wid / WCOLS, wc = wid % WCOLS;
    const int r0 = blockIdx.x * BM;

    const int s_row1 = t >> 2;
    const int s_row2 = (t + 256) >> 2;
    const int s_kg = t & 3;
    const int s_lf = ((t >> 2) & 15) + s_kg * 16;

    f32x4 acc[MF][NFW];
#pragma unroll
    for (int m = 0; m < MF; ++m)
#pragma unroll
        for (int n = 0; n < NFW; ++n) acc[m][n] = (f32x4){0.f, 0.f, 0.f, 0.f};

    for (int k0 = 0; k0 < K; k0 += 32) {
        const int ks = k0 >> 5;
#pragma unroll
        for (int uu = 0; uu < 2; ++uu) {
            const int row = uu ? s_row2 : s_row1;
            const int gr = r0 + row;
            float4 v0 = make_float4(0.f, 0.f, 0.f, 0.f), v1 = v0;
            if (gr < N) {
                const float* ap = &A[(size_t)gr * K + k0 + s_kg * 8];
                v0 = *(const float4*)ap;
                v1 = *(const float4*)(ap + 4);
            }
            short8 h, l;
            const float vv[8] = {v0.x, v0.y, v0.z, v0.w, v1.x, v1.y, v1.z, v1.w};
#pragma unroll
            for (int j = 0; j < 8; ++j) {
                const unsigned short hh = f2bf(vv[j]);
                h[j] = (short)hh;
                l[j] = (short)f2bf(vv[j] - bf2f(hh));
            }
            const int m = row >> 4;
            *(short8*)&AsH[m][s_lf * 8] = h;
            *(short8*)&AsL[m][s_lf * 8] = l;
        }
        __syncthreads();

        short8 bH[NFW], bL[NFW];
#pragma unroll
        for (int n = 0; n < NFW; ++n) {
            const int nfg = wc * NFW + n;
            const int base = ((ks * NFB + nfg) * 64 + lane) * 8;
            bH[n] = *(const short8*)&WpH[base];
            bL[n] = *(const short8*)&WpL[base];
        }
#pragma unroll
        for (int m = 0; m < MF; ++m) {
            const int mf = wr * MF + m;
            const short8 aH = *(const short8*)&AsH[mf][lane * 8];
            const short8 aL = *(const short8*)&AsL[mf][lane * 8];
#pragma unroll
            for (int n = 0; n < NFW; ++n) {
                acc[m][n] = __builtin_amdgcn_mfma_f32_16x16x32_bf16(aH, bH[n], acc[m][n], 0, 0, 0);
                acc[m][n] = __builtin_amdgcn_mfma_f32_16x16x32_bf16(aH, bL[n], acc[m][n], 0, 0, 0);
                acc[m][n] = __builtin_amdgcn_mfma_f32_16x16x32_bf16(aL, bH[n], acc[m][n], 0, 0, 0);
            }
        }
        __syncthreads();
    }

#pragma unroll
    for (int m = 0; m < MF; ++m) {
        const int row0 = r0 + wr * WTM + m * 16 + ((lane >> 4) << 2);
        float sc[4];
#pragma unroll
        for (int r = 0; r < 4; ++r) sc[r] = (row0 + r < N) ? scale[row0 + r] : 0.f;
#pragma unroll
        for (int n = 0; n < NFW; ++n) {
            const int cn = wc * (NFW * 16) + n * 16 + (lane & 15);
#pragma unroll
            for (int r = 0; r < 4; ++r) {
                if (row0 + r < N)
                    Out[(size_t)(row0 + r) * BN + cn] = acc[m][n][r] * sc[r];
            }
        }
    }
}

// CSR gather aggregation over PRE-SCALED H' (= dis*h), float4 per lane.
// COLS=128: 1 node/wave, 2 edge-subgroups x 32 lanes (32 lanes = one row).
// COLS=64 : 2 nodes/wave, per node 2 edge-subgroups x 16 lanes.
// UNIFORM control flow: both subgroups iterate exactly half=(remain+1)/2
// elements; esub1's possibly-out-of-range element is masked by VALUE
// (weight 0, safe row = node) so every __shfl source lane is active.
// Out[d] = relu( dis[d] * (sum_s H'[s] + H'[d]) + bias )
template <int COLS>
__global__ __launch_bounds__(256) void agg_gather(const int* __restrict__ rowptr,
                                                  const int* __restrict__ col,
                                                  const float* __restrict__ dis,
                                                  const float* __restrict__ Hs,
                                                  const float* __restrict__ bias,
                                                  float* __restrict__ Out, int N) {
    constexpr int NPW = (COLS == 128) ? 1 : 2;  // nodes per wave
    constexpr int LPN = 64 / NPW;               // lanes per node group
    constexpr int LPR = COLS / 4;               // lanes per row (float4)
    const int gw = (int)((blockIdx.x * blockDim.x + threadIdx.x) >> 6);
    const int lane = threadIdx.x & 63;
    const int sub = lane / LPN;    // node within wave
    const int nl = lane % LPN;     // lane within node group
    const int esub = nl / LPR;     // edge subgroup 0/1
    const int sl = nl % LPR;       // float4 index within row
    const int node = gw * NPW + sub;
    const int lgbase = sub * LPN;

    f32x4 acc = (f32x4){0.f, 0.f, 0.f, 0.f};
    int base = 0, len = 0;
    const int nodec = (node < N) ? node : 0;
    if (node < N) {
        base = rowptr[node];
        len = rowptr[node + 1] - base;
    }

    for (int j0 = 0; j0 < len; j0 += LPN) {
        const int remain = min(LPN, len - j0);
        // out-of-range lanes carry the node's own index (safe, hot row)
        const int sidx = (nl < remain) ? col[base + j0 + nl] : nodec;
        const int half = (remain + 1) >> 1;   // uniform trip count
        const int off = esub * half;          // esub0: [0,half), esub1: [half,2*half)
        int u = 0;
        for (; u + 8 <= half; u += 8) {
            f32x4 hv[8];
            float wv[8];
#pragma unroll
            for (int uu = 0; uu < 8; ++uu) {
                const int idx = off + u + uu;
                const int s = __shfl(sidx, lgbase + idx);
                wv[uu] = (idx < remain) ? 1.f : 0.f;
                hv[uu] = *(const f32x4*)(Hs + (size_t)s * COLS + sl * 4);
            }
#pragma unroll
            for (int uu = 0; uu < 8; ++uu) {
                acc.x = fmaf(hv[uu].x, wv[uu], acc.x);
                acc.y = fmaf(hv[uu].y, wv[uu], acc.y);
                acc.z = fmaf(hv[uu].z, wv[uu], acc.z);
                acc.w = fmaf(hv[uu].w, wv[uu], acc.w);
            }
        }
        for (; u + 4 <= half; u += 4) {
            f32x4 hv[4];
            float wv[4];
#pragma unroll
            for (int uu = 0; uu < 4; ++uu) {
                const int idx = off + u + uu;
                const int s = __shfl(sidx, lgbase + idx);
                wv[uu] = (idx < remain) ? 1.f : 0.f;
                hv[uu] = *(const f32x4*)(Hs + (size_t)s * COLS + sl * 4);
            }
#pragma unroll
            for (int uu = 0; uu < 4; ++uu) {
                acc.x = fmaf(hv[uu].x, wv[uu], acc.x);
                acc.y = fmaf(hv[uu].y, wv[uu], acc.y);
                acc.z = fmaf(hv[uu].z, wv[uu], acc.z);
                acc.w = fmaf(hv[uu].w, wv[uu], acc.w);
            }
        }
        for (; u < half; ++u) {
            const int idx = off + u;
            const int s = __shfl(sidx, lgbase + idx);
            const float w = (idx < remain) ? 1.f : 0.f;
            const f32x4 hv = *(const f32x4*)(Hs + (size_t)s * COLS + sl * 4);
            acc.x = fmaf(hv.x, w, acc.x);
            acc.y = fmaf(hv.y, w, acc.y);
            acc.z = fmaf(hv.z, w, acc.z);
            acc.w = fmaf(hv.w, w, acc.w);
        }
    }

    // combine the two edge-subgroup partials (butterfly over distance LPR)
    acc.x += __shfl_xor(acc.x, LPR);
    acc.y += __shfl_xor(acc.y, LPR);
    acc.z += __shfl_xor(acc.z, LPR);
    acc.w += __shfl_xor(acc.w, LPR);

    if (node < N && esub == 0) {
        const float dd = dis[node];
        const f32x4 hs = *(const f32x4*)(Hs + (size_t)node * COLS + sl * 4);
        const f32x4 bv = *(const f32x4*)(bias + sl * 4);
        f32x4 o;
        o.x = fmaxf(fmaf(acc.x + hs.x, dd, bv.x), 0.f);
        o.y = fmaxf(fmaf(acc.y + hs.y, dd, bv.y), 0.f);
        o.z = fmaxf(fmaf(acc.z + hs.z, dd, bv.z), 0.f);
        o.w = fmaxf(fmaf(acc.w + hs.w, dd, bv.w), 0.f);
        *(f32x4*)(Out + (size_t)node * COLS + sl * 4) = o;
    }
}

// mean-pool prep: wave = 32 consecutive rows, lane = column.
__global__ __launch_bounds__(256) void pool_kernel(const float* __restrict__ H,
                                                   const int* __restrict__ batch,
                                                   float* __restrict__ pooled,
                                                   float* __restrict__ cnt, int N) {
    const int c = threadIdx.x & 63;
    const int w = threadIdx.x >> 6;          // wave 0..3
    const int row0 = blockIdx.x * 128 + w * 32;
    if (row0 >= N) return;
    const int nr = min(32, N - row0);

    float v[32];
    int b[32];
#pragma unroll
    for (int i = 0; i < 32; ++i) {
        const int r = row0 + i;
        if (i < nr) {
            v[i] = H[(size_t)r * 64 + c];
            b[i] = batch[r];
        } else {
            v[i] = 0.f;
            b[i] = -1;
        }
    }
    int cur = b[0];
    float sum = 0.f, csum = 0.f;
#pragma unroll
    for (int i = 0; i < 32; ++i) {
        if (i < nr) {
            if (b[i] != cur) {
                atomicAdd(&pooled[cur * 64 + c], sum);
                if (c == 0) atomicAdd(&cnt[cur], csum);
                cur = b[i];
                sum = 0.f;
                csum = 0.f;
            }
            sum += v[i];
            csum += 1.f;
        }
    }
    atomicAdd(&pooled[cur * 64 + c], sum);
    if (c == 0) atomicAdd(&cnt[cur], csum);
}

__global__ __launch_bounds__(256) void final_kernel(const float* __restrict__ pooled,
                                                    const float* __restrict__ cnt,
                                                    const float* __restrict__ Wlin,
                                                    const float* __restrict__ blin,
                                                    float* __restrict__ out) {
    const int t = threadIdx.x;
    const int g = t >> 1, o = t & 1;
    const float inv = 1.0f / fmaxf(cnt[g], 1.0f);
    float s = 0.f;
#pragma unroll
    for (int j = 0; j < 64; ++j) s = fmaf(pooled[g * 64 + j], Wlin[j * 2 + o], s);
    out[t] = s * inv + blin[o];
}

extern "C" void kernel_launch(void* const* d_in, const int* in_sizes, int n_in,
                              void* d_out, int out_size, void* d_ws, size_t ws_size,
                              hipStream_t stream) {
    const float* x     = (const float*)d_in[0];
    const int*   edge  = (const int*)d_in[1];
    const int*   batch = (const int*)d_in[2];
    const float* W1    = (const float*)d_in[3];
    const float* b1    = (const float*)d_in[4];
    const float* W2    = (const float*)d_in[5];
    const float* b2    = (const float*)d_in[6];
    const float* Wlin  = (const float*)d_in[7];
    const float* blin  = (const float*)d_in[8];
    float* out = (float*)d_out;

    const int N = NN;
    const int E = in_sizes[1] / 2;
    const int* src = edge;
    const int* dst = edge + E;
    const int NB = (N + SCHUNK - 1) / SCHUNK;  // 98

    char* ws = (char*)d_ws;
    size_t off = 0;
    auto alloc = [&](size_t bytes) -> void* {
        void* p = ws + off;
        off += (bytes + 511) & ~(size_t)511;
        return p;
    };
    int*   deg    = (int*)alloc((size_t)N * 4);
    float* dis    = (float*)alloc((size_t)N * 4);
    int*   rowptr = (int*)alloc((size_t)(N + 1) * 4);
    int*   fill   = (int*)alloc((size_t)N * 4);
    int*   bsum   = (int*)alloc((size_t)NB * 4);
    int*   col    = (int*)alloc((size_t)E * 4);
    unsigned short* w1h = (unsigned short*)alloc((size_t)384 * 128 * 2);
    unsigned short* w1l = (unsigned short*)alloc((size_t)384 * 128 * 2);
    unsigned short* w2h = (unsigned short*)alloc((size_t)128 * 64 * 2);
    unsigned short* w2l = (unsigned short*)alloc((size_t)128 * 64 * 2);
    float* h1     = (float*)alloc((size_t)N * 128 * 4);
    float* agg1   = (float*)alloc((size_t)N * 128 * 4);
    float* pooled = (float*)alloc((size_t)NG * 64 * 4);
    float* cnt    = (float*)alloc((size_t)NG * 4);
    float* h2   = h1;
    float* agg2 = (float*)((char*)h1 + (size_t)N * 64 * 4);

    hipMemsetAsync(deg, 0, (size_t)N * 4, stream);
    hipMemsetAsync(fill, 0, (size_t)N * 4, stream);
    hipMemsetAsync(pooled, 0, (size_t)NG * 64 * 4, stream);
    hipMemsetAsync(cnt, 0, (size_t)NG * 4, stream);

    // weight packing (tiny, once per call)
    pack_w<<<(384 * 128 + 255) / 256, 256, 0, stream>>>(W1, w1h, w1l, 384, 128);
    pack_w<<<(128 * 64 + 255) / 256, 256, 0, stream>>>(W2, w2h, w2l, 128, 64);

    // degree + CSR build + normalization
    deg_kernel<<<2048, 256, 0, stream>>>(dst, deg, E);
    scan_part<<<NB, 256, 0, stream>>>(deg, bsum, N);
    scan_top<<<1, 128, 0, stream>>>(bsum, NB);
    scan_write<<<NB, 256, 0, stream>>>(deg, bsum, rowptr, dis, N, NB);
    csr_fill<<<2048, 256, 0, stream>>>(src, dst, rowptr, fill, col, E);

    const int gblocks = (N + 127) / 128;
    // layer 1 (gemm writes dis-prescaled h1')
    gemm_mfma<128><<<gblocks, 256, 0, stream>>>(x, w1h, w1l, dis, h1, N, 384);
    agg_gather<128><<<(N + 3) / 4, 256, 0, stream>>>(rowptr, col, dis, h1, b1, agg1, N);

    // layer 2 (h2' = dis * (agg1 @ W2), into h1's region)
    gemm_mfma<64><<<gblocks, 256, 0, stream>>>(agg1, w2h, w2l, dis, h2, N, 128);
    agg_gather<64><<<(N + 7) / 8, 256, 0, stream>>>(rowptr, col, dis, h2, b2, agg2, N);

    // pool + head
    pool_kernel<<<(N + 127) / 128, 256, 0, stream>>>(agg2, batch, pooled, cnt, N);
    final_kernel<<<1, 256, 0, stream>>>(pooled, cnt, Wlin, blin, out);
}

// Round 12
// 391.696 us; speedup vs baseline: 2.0433x; 1.2533x over previous
//
#include <hip/hip_runtime.h>

// GCN 2-layer + mean-pool + linear head, f32.
// Round 12: agg is L2-fill-BW-bound (two different MLP structures -> same
// 120us @ 401MB FETCH, 3.85 TB/s). Halve the bytes:
//   - gemm epilogue writes h' = dis*h as bf16 (RNE). h' feeds ONLY the
//     gather; agg outputs stay f32 so GEMM inputs keep full precision.
//   - agg_gather reads bf16x8 (16B/lane), converts via <<16, f32 accum.
//     4 edge-subgroups x (16|8) lanes/row, uniform trip ceil(remain/4),
//     value-masked tail (round-11 safe pattern), butterfly combine.
// Scan, CSR build, pool, final unchanged.

#define NN 100000
#define NG 128
#define SCHUNK 1024

typedef __attribute__((ext_vector_type(8))) short short8;
typedef __attribute__((ext_vector_type(8))) unsigned short u16x8;
typedef __attribute__((ext_vector_type(4))) float f32x4;

__device__ __forceinline__ unsigned short f2bf(float f) {
    union { float f; unsigned u; } v; v.f = f;
    unsigned r = v.u + 0x7fffu + ((v.u >> 16) & 1u);  // round-nearest-even
    return (unsigned short)(r >> 16);
}
__device__ __forceinline__ float bf2f(unsigned short h) {
    union { unsigned u; float f; } v; v.u = ((unsigned)h) << 16;
    return v.f;
}

__global__ __launch_bounds__(256) void deg_kernel(const int* __restrict__ dst,
                                                  int* __restrict__ deg, int E) {
    int i = blockIdx.x * blockDim.x + threadIdx.x;
    int stride = gridDim.x * blockDim.x;
    for (; i < E; i += stride) atomicAdd(&deg[dst[i]], 1);
}

// ---- 3-kernel exclusive scan of deg -> rowptr, fused dis = rsqrt(deg+1) ----
__global__ __launch_bounds__(256) void scan_part(const int* __restrict__ deg,
                                                 int* __restrict__ bsum, int N) {
    const int t = threadIdx.x;
    const int i = blockIdx.x * SCHUNK + t * 4;
    int4 v = make_int4(0, 0, 0, 0);
    if (i + 3 < N) v = *(const int4*)(deg + i);
    else {
        if (i < N) v.x = deg[i];
        if (i + 1 < N) v.y = deg[i + 1];
        if (i + 2 < N) v.z = deg[i + 2];
    }
    int s = v.x + v.y + v.z + v.w;
#pragma unroll
    for (int d = 1; d < 64; d <<= 1) s += __shfl_xor(s, d);
    __shared__ int ws[4];
    if ((t & 63) == 0) ws[t >> 6] = s;
    __syncthreads();
    if (t == 0) bsum[blockIdx.x] = ws[0] + ws[1] + ws[2] + ws[3];
}

__global__ __launch_bounds__(128) void scan_top(int* __restrict__ bsum, int NB) {
    __shared__ int sm[128];
    const int t = threadIdx.x;
    const int v = (t < NB) ? bsum[t] : 0;
    sm[t] = v;
    __syncthreads();
    for (int d = 1; d < 128; d <<= 1) {
        int a = (t >= d) ? sm[t - d] : 0;
        __syncthreads();
        sm[t] += a;
        __syncthreads();
    }
    if (t < NB) bsum[t] = sm[t] - v;  // exclusive
}

__global__ __launch_bounds__(256) void scan_write(const int* __restrict__ deg,
                                                  const int* __restrict__ bsum,
                                                  int* __restrict__ rowptr,
                                                  float* __restrict__ dis,
                                                  int N, int NB) {
    const int t = threadIdx.x;
    const int i = blockIdx.x * SCHUNK + t * 4;
    int4 v = make_int4(0, 0, 0, 0);
    if (i + 3 < N) v = *(const int4*)(deg + i);
    else {
        if (i < N) v.x = deg[i];
        if (i + 1 < N) v.y = deg[i + 1];
        if (i + 2 < N) v.z = deg[i + 2];
    }
    const int s = v.x + v.y + v.z + v.w;
    __shared__ int sm[256];
    sm[t] = s;
    __syncthreads();
    for (int d = 1; d < 256; d <<= 1) {
        int a = (t >= d) ? sm[t - d] : 0;
        __syncthreads();
        sm[t] += a;
        __syncthreads();
    }
    int run = bsum[blockIdx.x] + sm[t] - s;
    const int dv[4] = {v.x, v.y, v.z, v.w};
#pragma unroll
    for (int j = 0; j < 4; ++j) {
        if (i + j < N) {
            rowptr[i + j] = run;
            dis[i + j] = rsqrtf((float)dv[j] + 1.0f);
        }
        run += dv[j];
    }
    if (blockIdx.x == NB - 1 && t == 255) rowptr[N] = run;  // == E
}

__global__ __launch_bounds__(256) void csr_fill(const int* __restrict__ src,
                                                const int* __restrict__ dst,
                                                const int* __restrict__ rowptr,
                                                int* __restrict__ fill,
                                                int* __restrict__ col, int E) {
    int i = blockIdx.x * blockDim.x + threadIdx.x;
    int stride = gridDim.x * blockDim.x;
    for (; i < E; i += stride) {
        const int d = dst[i];
        const int pos = rowptr[d] + atomicAdd(&fill[d], 1);
        col[pos] = src[i];
    }
}

// One-time weight pack: W [K][BN] f32 -> hi/lo bf16 in MFMA fragment order.
__global__ __launch_bounds__(256) void pack_w(const float* __restrict__ W,
                                              unsigned short* __restrict__ packH,
                                              unsigned short* __restrict__ packL,
                                              int K, int BN) {
    const int idx = blockIdx.x * blockDim.x + threadIdx.x;
    if (idx >= K * BN) return;
    const int e = idx & 7;
    const int l = (idx >> 3) & 63;
    const int rest = idx >> 9;  // ks*NF + nf
    const int NF = BN >> 4;
    const int nf = rest % NF;
    const int ks = rest / NF;
    const int n = nf * 16 + (l & 15);
    const int k = ks * 32 + ((l >> 4) & 3) * 8 + e;
    const float v = W[(size_t)k * BN + n];
    const unsigned short h = f2bf(v);
    packH[idx] = h;
    packL[idx] = f2bf(v - bf2f(h));
}

// MFMA split-bf16 GEMM: A [N][K] f32 row-major, W pre-packed fragments.
// Epilogue: Out_bf16[row][col] = bf16( scale[row] * acc )  (dis pre-scale).
template <int BN>
__global__ __launch_bounds__(256) void gemm_mfma(const float* __restrict__ A,
                                                 const unsigned short* __restrict__ WpH,
                                                 const unsigned short* __restrict__ WpL,
                                                 const float* __restrict__ scale,
                                                 unsigned short* __restrict__ Out,
                                                 int N, int K) {
    constexpr int BM = 128;
    constexpr int WROWS = (BN == 128) ? 2 : 4;
    constexpr int WCOLS = (BN == 128) ? 2 : 1;
    constexpr int WTM = BM / WROWS;
    constexpr int MF = WTM / 16;
    constexpr int NFW = (BN / WCOLS) / 16;
    constexpr int NFB = BN / 16;

    __shared__ unsigned short AsH[8][512];
    __shared__ unsigned short AsL[8][512];

    const int t = threadIdx.x;
    const int wid = t >> 6, lane = t & 63;
    const int wr = wid / WCOLS, wc = wid % WCOLS;
    const int r0 = blockIdx.x * BM;

    const int s_row1 = t >> 2;
    const int s_row2 = (t + 256) >> 2;
    const int s_kg = t & 3;
    const int s_lf = ((t >> 2) & 15) + s_kg * 16;

    f32x4 acc[MF][NFW];
#pragma unroll
    for (int m = 0; m < MF; ++m)
#pragma unroll
        for (int n = 0; n < NFW; ++n) acc[m][n] = (f32x4){0.f, 0.f, 0.f, 0.f};

    for (int k0 = 0; k0 < K; k0 += 32) {
        const int ks = k0 >> 5;
#pragma unroll
        for (int uu = 0; uu < 2; ++uu) {
            const int row = uu ? s_row2 : s_row1;
            const int gr = r0 + row;
            float4 v0 = make_float4(0.f, 0.f, 0.f, 0.f), v1 = v0;
            if (gr < N) {
                const float* ap = &A[(size_t)gr * K + k0 + s_kg * 8];
                v0 = *(const float4*)ap;
                v1 = *(const float4*)(ap + 4);
            }
            short8 h, l;
            const float vv[8] = {v0.x, v0.y, v0.z, v0.w, v1.x, v1.y, v1.z, v1.w};
#pragma unroll
            for (int j = 0; j < 8; ++j) {
                const unsigned short hh = f2bf(vv[j]);
                h[j] = (short)hh;
                l[j] = (short)f2bf(vv[j] - bf2f(hh));
            }
            const int m = row >> 4;
            *(short8*)&AsH[m][s_lf * 8] = h;
            *(short8*)&AsL[m][s_lf * 8] = l;
        }
        __syncthreads();

        short8 bH[NFW], bL[NFW];
#pragma unroll
        for (int n = 0; n < NFW; ++n) {
            const int nfg = wc * NFW + n;
            const int base = ((ks * NFB + nfg) * 64 + lane) * 8;
            bH[n] = *(const short8*)&WpH[base];
            bL[n] = *(const short8*)&WpL[base];
        }
#pragma unroll
        for (int m = 0; m < MF; ++m) {
            const int mf = wr * MF + m;
            const short8 aH = *(const short8*)&AsH[mf][lane * 8];
            const short8 aL = *(const short8*)&AsL[mf][lane * 8];
#pragma unroll
            for (int n = 0; n < NFW; ++n) {
                acc[m][n] = __builtin_amdgcn_mfma_f32_16x16x32_bf16(aH, bH[n], acc[m][n], 0, 0, 0);
                acc[m][n] = __builtin_amdgcn_mfma_f32_16x16x32_bf16(aH, bL[n], acc[m][n], 0, 0, 0);
                acc[m][n] = __builtin_amdgcn_mfma_f32_16x16x32_bf16(aL, bH[n], acc[m][n], 0, 0, 0);
            }
        }
        __syncthreads();
    }

#pragma unroll
    for (int m = 0; m < MF; ++m) {
        const int row0 = r0 + wr * WTM + m * 16 + ((lane >> 4) << 2);
        float sc[4];
#pragma unroll
        for (int r = 0; r < 4; ++r) sc[r] = (row0 + r < N) ? scale[row0 + r] : 0.f;
#pragma unroll
        for (int n = 0; n < NFW; ++n) {
            const int cn = wc * (NFW * 16) + n * 16 + (lane & 15);
#pragma unroll
            for (int r = 0; r < 4; ++r) {
                if (row0 + r < N)
                    Out[(size_t)(row0 + r) * BN + cn] = f2bf(acc[m][n][r] * sc[r]);
            }
        }
    }
}

// CSR gather aggregation over PRE-SCALED bf16 H' (= bf16(dis*h)).
// 8 cols/lane (16B bf16x8). COLS=128: 1 node/wave, 4 subgroups x 16 lanes.
// COLS=64: 2 nodes/wave, 4 subgroups x 8 lanes each. Uniform trip count
// ceil(remain/4); out-of-range masked by VALUE (weight 0, safe row node).
// Out[d] = relu( dis[d] * (sum_s H'[s] + H'[d]) + bias )   [f32 output]
template <int COLS>
__global__ __launch_bounds__(256) void agg_gather(const int* __restrict__ rowptr,
                                                  const int* __restrict__ col,
                                                  const float* __restrict__ dis,
                                                  const unsigned short* __restrict__ Hs,
                                                  const float* __restrict__ bias,
                                                  float* __restrict__ Out, int N) {
    constexpr int NPW = (COLS == 128) ? 1 : 2;  // nodes per wave
    constexpr int LPN = 64 / NPW;               // lanes per node group
    constexpr int LPR = COLS / 8;               // lanes per row (bf16x8)
    constexpr int NSG = LPN / LPR;              // 4 edge subgroups
    const int gw = (int)((blockIdx.x * blockDim.x + threadIdx.x) >> 6);
    const int lane = threadIdx.x & 63;
    const int sub = lane / LPN;    // node within wave
    const int nl = lane % LPN;     // lane within node group
    const int esub = nl / LPR;     // edge subgroup 0..3
    const int sl = nl % LPR;       // 8-col group within row
    const int node = gw * NPW + sub;
    const int lgbase = sub * LPN;

    float acc[8];
#pragma unroll
    for (int k = 0; k < 8; ++k) acc[k] = 0.f;

    int base = 0, len = 0;
    const int nodec = (node < N) ? node : 0;
    if (node < N) {
        base = rowptr[node];
        len = rowptr[node + 1] - base;
    }

    for (int j0 = 0; j0 < len; j0 += LPN) {
        const int remain = min(LPN, len - j0);
        // out-of-range lanes carry the node's own index (safe, hot row)
        const int sidx = (nl < remain) ? col[base + j0 + nl] : nodec;
        const int qtr = (remain + NSG - 1) / NSG;  // uniform trip count
        const int off = esub * qtr;                // 4*qtr <= LPN always
        int u = 0;
        for (; u + 8 <= qtr; u += 8) {
            u16x8 hv[8];
            float wv[8];
#pragma unroll
            for (int b = 0; b < 8; ++b) {
                const int idx = off + u + b;
                const int s = __shfl(sidx, lgbase + idx);
                wv[b] = (idx < remain) ? 1.f : 0.f;
                hv[b] = *(const u16x8*)(Hs + (size_t)s * COLS + sl * 8);
            }
#pragma unroll
            for (int b = 0; b < 8; ++b)
#pragma unroll
                for (int k = 0; k < 8; ++k)
                    acc[k] = fmaf(bf2f(hv[b][k]), wv[b], acc[k]);
        }
        for (; u + 4 <= qtr; u += 4) {
            u16x8 hv[4];
            float wv[4];
#pragma unroll
            for (int b = 0; b < 4; ++b) {
                const int idx = off + u + b;
                const int s = __shfl(sidx, lgbase + idx);
                wv[b] = (idx < remain) ? 1.f : 0.f;
                hv[b] = *(const u16x8*)(Hs + (size_t)s * COLS + sl * 8);
            }
#pragma unroll
            for (int b = 0; b < 4; ++b)
#pragma unroll
                for (int k = 0; k < 8; ++k)
                    acc[k] = fmaf(bf2f(hv[b][k]), wv[b], acc[k]);
        }
        for (; u < qtr; ++u) {
            const int idx = off + u;
            const int s = __shfl(sidx, lgbase + idx);
            const float w = (idx < remain) ? 1.f : 0.f;
            const u16x8 hv = *(const u16x8*)(Hs + (size_t)s * COLS + sl * 8);
#pragma unroll
            for (int k = 0; k < 8; ++k)
                acc[k] = fmaf(bf2f(hv[k]), w, acc[k]);
        }
    }

    // combine the 4 edge-subgroup partials (butterfly at LPR, 2*LPR)
#pragma unroll
    for (int k = 0; k < 8; ++k) {
        acc[k] += __shfl_xor(acc[k], LPR);
        acc[k] += __shfl_xor(acc[k], 2 * LPR);
    }

    if (node < N && esub == 0) {
        const float dd = dis[node];
        const u16x8 hsb = *(const u16x8*)(Hs + (size_t)node * COLS + sl * 8);
        const f32x4 bv0 = *(const f32x4*)(bias + sl * 8);
        const f32x4 bv1 = *(const f32x4*)(bias + sl * 8 + 4);
        f32x4 o0, o1;
#pragma unroll
        for (int k = 0; k < 4; ++k) {
            o0[k] = fmaxf(fmaf(acc[k] + bf2f(hsb[k]), dd, bv0[k]), 0.f);
            o1[k] = fmaxf(fmaf(acc[k + 4] + bf2f(hsb[k + 4]), dd, bv1[k]), 0.f);
        }
        *(f32x4*)(Out + (size_t)node * COLS + sl * 8) = o0;
        *(f32x4*)(Out + (size_t)node * COLS + sl * 8 + 4) = o1;
    }
}

// mean-pool prep: wave = 32 consecutive rows, lane = column.
__global__ __launch_bounds__(256) void pool_kernel(const float* __restrict__ H,
                                                   const int* __restrict__ batch,
                                                   float* __restrict__ pooled,
                                                   float* __restrict__ cnt, int N) {
    const int c = threadIdx.x & 63;
    const int w = threadIdx.x >> 6;          // wave 0..3
    const int row0 = blockIdx.x * 128 + w * 32;
    if (row0 >= N) return;
    const int nr = min(32, N - row0);

    float v[32];
    int b[32];
#pragma unroll
    for (int i = 0; i < 32; ++i) {
        const int r = row0 + i;
        if (i < nr) {
            v[i] = H[(size_t)r * 64 + c];
            b[i] = batch[r];
        } else {
            v[i] = 0.f;
            b[i] = -1;
        }
    }
    int cur = b[0];
    float sum = 0.f, csum = 0.f;
#pragma unroll
    for (int i = 0; i < 32; ++i) {
        if (i < nr) {
            if (b[i] != cur) {
                atomicAdd(&pooled[cur * 64 + c], sum);
                if (c == 0) atomicAdd(&cnt[cur], csum);
                cur = b[i];
                sum = 0.f;
                csum = 0.f;
            }
            sum += v[i];
            csum += 1.f;
        }
    }
    atomicAdd(&pooled[cur * 64 + c], sum);
    if (c == 0) atomicAdd(&cnt[cur], csum);
}

__global__ __launch_bounds__(256) void final_kernel(const float* __restrict__ pooled,
                                                    const float* __restrict__ cnt,
                                                    const float* __restrict__ Wlin,
                                                    const float* __restrict__ blin,
                                                    float* __restrict__ out) {
    const int t = threadIdx.x;
    const int g = t >> 1, o = t & 1;
    const float inv = 1.0f / fmaxf(cnt[g], 1.0f);
    float s = 0.f;
#pragma unroll
    for (int j = 0; j < 64; ++j) s = fmaf(pooled[g * 64 + j], Wlin[j * 2 + o], s);
    out[t] = s * inv + blin[o];
}

extern "C" void kernel_launch(void* const* d_in, const int* in_sizes, int n_in,
                              void* d_out, int out_size, void* d_ws, size_t ws_size,
                              hipStream_t stream) {
    const float* x     = (const float*)d_in[0];
    const int*   edge  = (const int*)d_in[1];
    const int*   batch = (const int*)d_in[2];
    const float* W1    = (const float*)d_in[3];
    const float* b1    = (const float*)d_in[4];
    const float* W2    = (const float*)d_in[5];
    const float* b2    = (const float*)d_in[6];
    const float* Wlin  = (const float*)d_in[7];
    const float* blin  = (const float*)d_in[8];
    float* out = (float*)d_out;

    const int N = NN;
    const int E = in_sizes[1] / 2;
    const int* src = edge;
    const int* dst = edge + E;
    const int NB = (N + SCHUNK - 1) / SCHUNK;  // 98

    char* ws = (char*)d_ws;
    size_t off = 0;
    auto alloc = [&](size_t bytes) -> void* {
        void* p = ws + off;
        off += (bytes + 511) & ~(size_t)511;
        return p;
    };
    int*   deg    = (int*)alloc((size_t)N * 4);
    float* dis    = (float*)alloc((size_t)N * 4);
    int*   rowptr = (int*)alloc((size_t)(N + 1) * 4);
    int*   fill   = (int*)alloc((size_t)N * 4);
    int*   bsum   = (int*)alloc((size_t)NB * 4);
    int*   col    = (int*)alloc((size_t)E * 4);
    unsigned short* w1h = (unsigned short*)alloc((size_t)384 * 128 * 2);
    unsigned short* w1l = (unsigned short*)alloc((size_t)384 * 128 * 2);
    unsigned short* w2h = (unsigned short*)alloc((size_t)128 * 64 * 2);
    unsigned short* w2l = (unsigned short*)alloc((size_t)128 * 64 * 2);
    unsigned short* h1bf = (unsigned short*)alloc((size_t)N * 128 * 2);  // 25.6 MB
    float* agg1   = (float*)alloc((size_t)N * 128 * 4);                  // 51.2 MB
    float* pooled = (float*)alloc((size_t)NG * 64 * 4);
    float* cnt    = (float*)alloc((size_t)NG * 4);
    // layer-2 reuse: h2bf in h1bf's region (dead after agg<128>);
    // agg2 in agg1's region (agg1 dead after gemm2 reads it).
    unsigned short* h2bf = h1bf;
    float* agg2 = agg1;

    hipMemsetAsync(deg, 0, (size_t)N * 4, stream);
    hipMemsetAsync(fill, 0, (size_t)N * 4, stream);
    hipMemsetAsync(pooled, 0, (size_t)NG * 64 * 4, stream);
    hipMemsetAsync(cnt, 0, (size_t)NG * 4, stream);

    // weight packing (tiny, once per call)
    pack_w<<<(384 * 128 + 255) / 256, 256, 0, stream>>>(W1, w1h, w1l, 384, 128);
    pack_w<<<(128 * 64 + 255) / 256, 256, 0, stream>>>(W2, w2h, w2l, 128, 64);

    // degree + CSR build + normalization
    deg_kernel<<<2048, 256, 0, stream>>>(dst, deg, E);
    scan_part<<<NB, 256, 0, stream>>>(deg, bsum, N);
    scan_top<<<1, 128, 0, stream>>>(bsum, NB);
    scan_write<<<NB, 256, 0, stream>>>(deg, bsum, rowptr, dis, N, NB);
    csr_fill<<<2048, 256, 0, stream>>>(src, dst, rowptr, fill, col, E);

    const int gblocks = (N + 127) / 128;
    // layer 1 (gemm writes dis-prescaled bf16 h1')
    gemm_mfma<128><<<gblocks, 256, 0, stream>>>(x, w1h, w1l, dis, h1bf, N, 384);
    agg_gather<128><<<(N + 3) / 4, 256, 0, stream>>>(rowptr, col, dis, h1bf, b1, agg1, N);

    // layer 2 (gemm reads f32 agg1, writes dis-prescaled bf16 h2')
    gemm_mfma<64><<<gblocks, 256, 0, stream>>>(agg1, w2h, w2l, dis, h2bf, N, 128);
    agg_gather<64><<<(N + 7) / 8, 256, 0, stream>>>(rowptr, col, dis, h2bf, b2, agg2, N);

    // pool + head
    pool_kernel<<<(N + 127) / 128, 256, 0, stream>>>(agg2, batch, pooled, cnt, N);
    final_kernel<<<1, 256, 0, stream>>>(pooled, cnt, Wlin, blin, out);
}

// Round 13
// 282.301 us; speedup vs baseline: 2.8351x; 1.3875x over previous
//
#include <hip/hip_runtime.h>

// GCN 2-layer + mean-pool + linear head, f32.
// Round 13: CSR build was 170us (csr_fill 125us: 1.6M random 4B stores ->
// 102MB write-allocate + 1.6M random atomics; deg another 1.6M atomics).
// Replace deg/scan x3/csr_fill with bucketed counting sort:
//   - bucket_scatter: per-block LDS histogram over 391 buckets (dst>>8),
//     one global atomicAdd per (block,bucket) chunk reservation, pair
//     writes land consecutively per bucket region (lines fill).
//   - bucket_scan: 391-entry scan -> bucket bases (= rowptr at boundaries).
//   - bucket_build: per-bucket LDS node histogram + LDS scan -> rowptr/dis,
//     then col fill into the bucket's CONTIGUOUS col region (LDS counters).
// GEMMs (MFMA split-bf16, bf16 dis-prescaled output), bf16 agg_gather,
// pool, final unchanged from round 12.

#define NN 100000
#define NG 128
#define BNODES 256
#define NBUK ((NN + BNODES - 1) / BNODES)   // 391
#define BCAP 6144                            // >= bucket edges (~4092 +32sigma)

typedef __attribute__((ext_vector_type(8))) short short8;
typedef __attribute__((ext_vector_type(8))) unsigned short u16x8;
typedef __attribute__((ext_vector_type(4))) float f32x4;

__device__ __forceinline__ unsigned short f2bf(float f) {
    union { float f; unsigned u; } v; v.f = f;
    unsigned r = v.u + 0x7fffu + ((v.u >> 16) & 1u);  // round-nearest-even
    return (unsigned short)(r >> 16);
}
__device__ __forceinline__ float bf2f(unsigned short h) {
    union { unsigned u; float f; } v; v.u = ((unsigned)h) << 16;
    return v.f;
}

// ---- pass 1: bucket edges by dst>>8 with privatized histograms ----
__global__ __launch_bounds__(256) void bucket_scatter(const int* __restrict__ src,
                                                      const int* __restrict__ dst,
                                                      int* __restrict__ bcnt,
                                                      int2* __restrict__ pairs, int E) {
    __shared__ int hist[NBUK];
    __shared__ int lbase[NBUK];
    __shared__ int lfill[NBUK];
    const int t = threadIdx.x;
    const int chunk = (E + gridDim.x - 1) / gridDim.x;
    const int lo = blockIdx.x * chunk;
    const int hi = min(E, lo + chunk);
    for (int b = t; b < NBUK; b += 256) { hist[b] = 0; lfill[b] = 0; }
    __syncthreads();
    for (int i = lo + t; i < hi; i += 256)
        atomicAdd(&hist[dst[i] >> 8], 1);
    __syncthreads();
    for (int b = t; b < NBUK; b += 256)
        lbase[b] = hist[b] ? atomicAdd(&bcnt[b], hist[b]) : 0;
    __syncthreads();
    for (int i = lo + t; i < hi; i += 256) {
        const int s = src[i], d = dst[i];
        const int b = d >> 8;
        const int off = atomicAdd(&lfill[b], 1);
        pairs[(size_t)b * BCAP + lbase[b] + off] = make_int2(s, d);
    }
}

// ---- pass 2a: exclusive scan of bucket counts -> bucket bases ----
__global__ __launch_bounds__(512) void bucket_scan(const int* __restrict__ bcnt,
                                                   int* __restrict__ bbase,
                                                   int* __restrict__ rowptr,
                                                   int N, int E) {
    __shared__ int sm[512];
    const int t = threadIdx.x;
    sm[t] = (t < NBUK) ? bcnt[t] : 0;
    __syncthreads();
    for (int d = 1; d < 512; d <<= 1) {
        int a = (t >= d) ? sm[t - d] : 0;
        __syncthreads();
        sm[t] += a;
        __syncthreads();
    }
    if (t <= NBUK) bbase[t] = (t == 0) ? 0 : sm[t - 1];
    if (t == 0) rowptr[N] = E;
}

// ---- pass 2b: per-bucket node histogram + scan -> rowptr/dis, col fill ----
__global__ __launch_bounds__(256) void bucket_build(const int2* __restrict__ pairs,
                                                    const int* __restrict__ bcnt,
                                                    const int* __restrict__ bbase,
                                                    int* __restrict__ rowptr,
                                                    float* __restrict__ dis,
                                                    int* __restrict__ col, int N) {
    __shared__ int cnt[BNODES];
    __shared__ int sm[BNODES];
    __shared__ int pref[BNODES];
    __shared__ int fillc[BNODES];
    const int b = blockIdx.x;
    const int t = threadIdx.x;
    const int nbase = b * BNODES;
    const int ecnt = bcnt[b];
    const int2* ep = pairs + (size_t)b * BCAP;
    const int gbase = bbase[b];

    cnt[t] = 0;
    fillc[t] = 0;
    __syncthreads();
    for (int i = t; i < ecnt; i += 256)
        atomicAdd(&cnt[ep[i].y & (BNODES - 1)], 1);
    __syncthreads();
    sm[t] = cnt[t];
    __syncthreads();
    for (int d = 1; d < 256; d <<= 1) {
        int a = (t >= d) ? sm[t - d] : 0;
        __syncthreads();
        sm[t] += a;
        __syncthreads();
    }
    pref[t] = sm[t] - cnt[t];
    const int node = nbase + t;
    if (node < N) {
        rowptr[node] = gbase + pref[t];
        dis[node] = rsqrtf((float)cnt[t] + 1.0f);
    }
    __syncthreads();
    for (int i = t; i < ecnt; i += 256) {
        const int2 e = ep[i];
        const int d = e.y & (BNODES - 1);
        const int pos = gbase + pref[d] + atomicAdd(&fillc[d], 1);
        col[pos] = e.x;
    }
}

// One-time weight pack: W [K][BN] f32 -> hi/lo bf16 in MFMA fragment order.
__global__ __launch_bounds__(256) void pack_w(const float* __restrict__ W,
                                              unsigned short* __restrict__ packH,
                                              unsigned short* __restrict__ packL,
                                              int K, int BN) {
    const int idx = blockIdx.x * blockDim.x + threadIdx.x;
    if (idx >= K * BN) return;
    const int e = idx & 7;
    const int l = (idx >> 3) & 63;
    const int rest = idx >> 9;  // ks*NF + nf
    const int NF = BN >> 4;
    const int nf = rest % NF;
    const int ks = rest / NF;
    const int n = nf * 16 + (l & 15);
    const int k = ks * 32 + ((l >> 4) & 3) * 8 + e;
    const float v = W[(size_t)k * BN + n];
    const unsigned short h = f2bf(v);
    packH[idx] = h;
    packL[idx] = f2bf(v - bf2f(h));
}

// MFMA split-bf16 GEMM: A [N][K] f32 row-major, W pre-packed fragments.
// Epilogue: Out_bf16[row][col] = bf16( scale[row] * acc )  (dis pre-scale).
template <int BN>
__global__ __launch_bounds__(256) void gemm_mfma(const float* __restrict__ A,
                                                 const unsigned short* __restrict__ WpH,
                                                 const unsigned short* __restrict__ WpL,
                                                 const float* __restrict__ scale,
                                                 unsigned short* __restrict__ Out,
                                                 int N, int K) {
    constexpr int BM = 128;
    constexpr int WROWS = (BN == 128) ? 2 : 4;
    constexpr int WCOLS = (BN == 128) ? 2 : 1;
    constexpr int WTM = BM / WROWS;
    constexpr int MF = WTM / 16;
    constexpr int NFW = (BN / WCOLS) / 16;
    constexpr int NFB = BN / 16;

    __shared__ unsigned short AsH[8][512];
    __shared__ unsigned short AsL[8][512];

    const int t = threadIdx.x;
    const int wid = t >> 6, lane = t & 63;
    const int wr = wid / WCOLS, wc = wid % WCOLS;
    const int r0 = blockIdx.x * BM;

    const int s_row1 = t >> 2;
    const int s_row2 = (t + 256) >> 2;
    const int s_kg = t & 3;
    const int s_lf = ((t >> 2) & 15) + s_kg * 16;

    f32x4 acc[MF][NFW];
#pragma unroll
    for (int m = 0; m < MF; ++m)
#pragma unroll
        for (int n = 0; n < NFW; ++n) acc[m][n] = (f32x4){0.f, 0.f, 0.f, 0.f};

    for (int k0 = 0; k0 < K; k0 += 32) {
        const int ks = k0 >> 5;
#pragma unroll
        for (int uu = 0; uu < 2; ++uu) {
            const int row = uu ? s_row2 : s_row1;
            const int gr = r0 + row;
            float4 v0 = make_float4(0.f, 0.f, 0.f, 0.f), v1 = v0;
            if (gr < N) {
                const float* ap = &A[(size_t)gr * K + k0 + s_kg * 8];
                v0 = *(const float4*)ap;
                v1 = *(const float4*)(ap + 4);
            }
            short8 h, l;
            const float vv[8] = {v0.x, v0.y, v0.z, v0.w, v1.x, v1.y, v1.z, v1.w};
#pragma unroll
            for (int j = 0; j < 8; ++j) {
                const unsigned short hh = f2bf(vv[j]);
                h[j] = (short)hh;
                l[j] = (short)f2bf(vv[j] - bf2f(hh));
            }
            const int m = row >> 4;
            *(short8*)&AsH[m][s_lf * 8] = h;
            *(short8*)&AsL[m][s_lf * 8] = l;
        }
        __syncthreads();

        short8 bH[NFW], bL[NFW];
#pragma unroll
        for (int n = 0; n < NFW; ++n) {
            const int nfg = wc * NFW + n;
            const int base = ((ks * NFB + nfg) * 64 + lane) * 8;
            bH[n] = *(const short8*)&WpH[base];
            bL[n] = *(const short8*)&WpL[base];
        }
#pragma unroll
        for (int m = 0; m < MF; ++m) {
            const int mf = wr * MF + m;
            const short8 aH = *(const short8*)&AsH[mf][lane * 8];
            const short8 aL = *(const short8*)&AsL[mf][lane * 8];
#pragma unroll
            for (int n = 0; n < NFW; ++n) {
                acc[m][n] = __builtin_amdgcn_mfma_f32_16x16x32_bf16(aH, bH[n], acc[m][n], 0, 0, 0);
                acc[m][n] = __builtin_amdgcn_mfma_f32_16x16x32_bf16(aH, bL[n], acc[m][n], 0, 0, 0);
                acc[m][n] = __builtin_amdgcn_mfma_f32_16x16x32_bf16(aL, bH[n], acc[m][n], 0, 0, 0);
            }
        }
        __syncthreads();
    }

#pragma unroll
    for (int m = 0; m < MF; ++m) {
        const int row0 = r0 + wr * WTM + m * 16 + ((lane >> 4) << 2);
        float sc[4];
#pragma unroll
        for (int r = 0; r < 4; ++r) sc[r] = (row0 + r < N) ? scale[row0 + r] : 0.f;
#pragma unroll
        for (int n = 0; n < NFW; ++n) {
            const int cn = wc * (NFW * 16) + n * 16 + (lane & 15);
#pragma unroll
            for (int r = 0; r < 4; ++r) {
                if (row0 + r < N)
                    Out[(size_t)(row0 + r) * BN + cn] = f2bf(acc[m][n][r] * sc[r]);
            }
        }
    }
}

// CSR gather aggregation over PRE-SCALED bf16 H' (= bf16(dis*h)).
// 8 cols/lane (16B bf16x8). COLS=128: 1 node/wave, 4 subgroups x 16 lanes.
// COLS=64: 2 nodes/wave, 4 subgroups x 8 lanes each. Uniform trip count
// ceil(remain/4); out-of-range masked by VALUE (weight 0, safe row node).
// Out[d] = relu( dis[d] * (sum_s H'[s] + H'[d]) + bias )   [f32 output]
template <int COLS>
__global__ __launch_bounds__(256) void agg_gather(const int* __restrict__ rowptr,
                                                  const int* __restrict__ col,
                                                  const float* __restrict__ dis,
                                                  const unsigned short* __restrict__ Hs,
                                                  const float* __restrict__ bias,
                                                  float* __restrict__ Out, int N) {
    constexpr int NPW = (COLS == 128) ? 1 : 2;  // nodes per wave
    constexpr int LPN = 64 / NPW;               // lanes per node group
    constexpr int LPR = COLS / 8;               // lanes per row (bf16x8)
    constexpr int NSG = LPN / LPR;              // 4 edge subgroups
    const int gw = (int)((blockIdx.x * blockDim.x + threadIdx.x) >> 6);
    const int lane = threadIdx.x & 63;
    const int sub = lane / LPN;    // node within wave
    const int nl = lane % LPN;     // lane within node group
    const int esub = nl / LPR;     // edge subgroup 0..3
    const int sl = nl % LPR;       // 8-col group within row
    const int node = gw * NPW + sub;
    const int lgbase = sub * LPN;

    float acc[8];
#pragma unroll
    for (int k = 0; k < 8; ++k) acc[k] = 0.f;

    int base = 0, len = 0;
    const int nodec = (node < N) ? node : 0;
    if (node < N) {
        base = rowptr[node];
        len = rowptr[node + 1] - base;
    }

    for (int j0 = 0; j0 < len; j0 += LPN) {
        const int remain = min(LPN, len - j0);
        const int sidx = (nl < remain) ? col[base + j0 + nl] : nodec;
        const int qtr = (remain + NSG - 1) / NSG;  // uniform trip count
        const int off = esub * qtr;
        int u = 0;
        for (; u + 8 <= qtr; u += 8) {
            u16x8 hv[8];
            float wv[8];
#pragma unroll
            for (int b = 0; b < 8; ++b) {
                const int idx = off + u + b;
                const int s = __shfl(sidx, lgbase + idx);
                wv[b] = (idx < remain) ? 1.f : 0.f;
                hv[b] = *(const u16x8*)(Hs + (size_t)s * COLS + sl * 8);
            }
#pragma unroll
            for (int b = 0; b < 8; ++b)
#pragma unroll
                for (int k = 0; k < 8; ++k)
                    acc[k] = fmaf(bf2f(hv[b][k]), wv[b], acc[k]);
        }
        for (; u + 4 <= qtr; u += 4) {
            u16x8 hv[4];
            float wv[4];
#pragma unroll
            for (int b = 0; b < 4; ++b) {
                const int idx = off + u + b;
                const int s = __shfl(sidx, lgbase + idx);
                wv[b] = (idx < remain) ? 1.f : 0.f;
                hv[b] = *(const u16x8*)(Hs + (size_t)s * COLS + sl * 8);
            }
#pragma unroll
            for (int b = 0; b < 4; ++b)
#pragma unroll
                for (int k = 0; k < 8; ++k)
                    acc[k] = fmaf(bf2f(hv[b][k]), wv[b], acc[k]);
        }
        for (; u < qtr; ++u) {
            const int idx = off + u;
            const int s = __shfl(sidx, lgbase + idx);
            const float w = (idx < remain) ? 1.f : 0.f;
            const u16x8 hv = *(const u16x8*)(Hs + (size_t)s * COLS + sl * 8);
#pragma unroll
            for (int k = 0; k < 8; ++k)
                acc[k] = fmaf(bf2f(hv[k]), w, acc[k]);
        }
    }

#pragma unroll
    for (int k = 0; k < 8; ++k) {
        acc[k] += __shfl_xor(acc[k], LPR);
        acc[k] += __shfl_xor(acc[k], 2 * LPR);
    }

    if (node < N && esub == 0) {
        const float dd = dis[node];
        const u16x8 hsb = *(const u16x8*)(Hs + (size_t)node * COLS + sl * 8);
        const f32x4 bv0 = *(const f32x4*)(bias + sl * 8);
        const f32x4 bv1 = *(const f32x4*)(bias + sl * 8 + 4);
        f32x4 o0, o1;
#pragma unroll
        for (int k = 0; k < 4; ++k) {
            o0[k] = fmaxf(fmaf(acc[k] + bf2f(hsb[k]), dd, bv0[k]), 0.f);
            o1[k] = fmaxf(fmaf(acc[k + 4] + bf2f(hsb[k + 4]), dd, bv1[k]), 0.f);
        }
        *(f32x4*)(Out + (size_t)node * COLS + sl * 8) = o0;
        *(f32x4*)(Out + (size_t)node * COLS + sl * 8 + 4) = o1;
    }
}

// mean-pool prep: wave = 32 consecutive rows, lane = column.
__global__ __launch_bounds__(256) void pool_kernel(const float* __restrict__ H,
                                                   const int* __restrict__ batch,
                                                   float* __restrict__ pooled,
                                                   float* __restrict__ cnt, int N) {
    const int c = threadIdx.x & 63;
    const int w = threadIdx.x >> 6;          // wave 0..3
    const int row0 = blockIdx.x * 128 + w * 32;
    if (row0 >= N) return;
    const int nr = min(32, N - row0);

    float v[32];
    int b[32];
#pragma unroll
    for (int i = 0; i < 32; ++i) {
        const int r = row0 + i;
        if (i < nr) {
            v[i] = H[(size_t)r * 64 + c];
            b[i] = batch[r];
        } else {
            v[i] = 0.f;
            b[i] = -1;
        }
    }
    int cur = b[0];
    float sum = 0.f, csum = 0.f;
#pragma unroll
    for (int i = 0; i < 32; ++i) {
        if (i < nr) {
            if (b[i] != cur) {
                atomicAdd(&pooled[cur * 64 + c], sum);
                if (c == 0) atomicAdd(&cnt[cur], csum);
                cur = b[i];
                sum = 0.f;
                csum = 0.f;
            }
            sum += v[i];
            csum += 1.f;
        }
    }
    atomicAdd(&pooled[cur * 64 + c], sum);
    if (c == 0) atomicAdd(&cnt[cur], csum);
}

__global__ __launch_bounds__(256) void final_kernel(const float* __restrict__ pooled,
                                                    const float* __restrict__ cnt,
                                                    const float* __restrict__ Wlin,
                                                    const float* __restrict__ blin,
                                                    float* __restrict__ out) {
    const int t = threadIdx.x;
    const int g = t >> 1, o = t & 1;
    const float inv = 1.0f / fmaxf(cnt[g], 1.0f);
    float s = 0.f;
#pragma unroll
    for (int j = 0; j < 64; ++j) s = fmaf(pooled[g * 64 + j], Wlin[j * 2 + o], s);
    out[t] = s * inv + blin[o];
}

extern "C" void kernel_launch(void* const* d_in, const int* in_sizes, int n_in,
                              void* d_out, int out_size, void* d_ws, size_t ws_size,
                              hipStream_t stream) {
    const float* x     = (const float*)d_in[0];
    const int*   edge  = (const int*)d_in[1];
    const int*   batch = (const int*)d_in[2];
    const float* W1    = (const float*)d_in[3];
    const float* b1    = (const float*)d_in[4];
    const float* W2    = (const float*)d_in[5];
    const float* b2    = (const float*)d_in[6];
    const float* Wlin  = (const float*)d_in[7];
    const float* blin  = (const float*)d_in[8];
    float* out = (float*)d_out;

    const int N = NN;
    const int E = in_sizes[1] / 2;
    const int* src = edge;
    const int* dst = edge + E;

    char* ws = (char*)d_ws;
    size_t off = 0;
    auto alloc = [&](size_t bytes) -> void* {
        void* p = ws + off;
        off += (bytes + 511) & ~(size_t)511;
        return p;
    };
    float* dis    = (float*)alloc((size_t)N * 4);
    int*   rowptr = (int*)alloc((size_t)(N + 1) * 4);
    int*   bcnt   = (int*)alloc((size_t)NBUK * 4);
    int*   bbase  = (int*)alloc((size_t)(NBUK + 1) * 4);
    int*   col    = (int*)alloc((size_t)E * 4);                 // 6.4 MB
    int2*  pairs  = (int2*)alloc((size_t)NBUK * BCAP * 8);      // 19.2 MB
    unsigned short* w1h = (unsigned short*)alloc((size_t)384 * 128 * 2);
    unsigned short* w1l = (unsigned short*)alloc((size_t)384 * 128 * 2);
    unsigned short* w2h = (unsigned short*)alloc((size_t)128 * 64 * 2);
    unsigned short* w2l = (unsigned short*)alloc((size_t)128 * 64 * 2);
    unsigned short* h1bf = (unsigned short*)alloc((size_t)N * 128 * 2);  // 25.6 MB
    float* agg1   = (float*)alloc((size_t)N * 128 * 4);                  // 51.2 MB
    float* pooled = (float*)alloc((size_t)NG * 64 * 4);
    float* cnt    = (float*)alloc((size_t)NG * 4);
    unsigned short* h2bf = h1bf;   // layer-2 reuse (h1bf dead after agg<128>)
    float* agg2 = agg1;            // agg1 dead after gemm2 reads it

    hipMemsetAsync(bcnt, 0, (size_t)NBUK * 4, stream);
    hipMemsetAsync(pooled, 0, (size_t)NG * 64 * 4, stream);
    hipMemsetAsync(cnt, 0, (size_t)NG * 4, stream);

    // weight packing (tiny, once per call)
    pack_w<<<(384 * 128 + 255) / 256, 256, 0, stream>>>(W1, w1h, w1l, 384, 128);
    pack_w<<<(128 * 64 + 255) / 256, 256, 0, stream>>>(W2, w2h, w2l, 128, 64);

    // CSR build via bucketed counting sort (no global random atomics)
    bucket_scatter<<<512, 256, 0, stream>>>(src, dst, bcnt, pairs, E);
    bucket_scan<<<1, 512, 0, stream>>>(bcnt, bbase, rowptr, N, E);
    bucket_build<<<NBUK, 256, 0, stream>>>(pairs, bcnt, bbase, rowptr, dis, col, N);

    const int gblocks = (N + 127) / 128;
    // layer 1 (gemm writes dis-prescaled bf16 h1')
    gemm_mfma<128><<<gblocks, 256, 0, stream>>>(x, w1h, w1l, dis, h1bf, N, 384);
    agg_gather<128><<<(N + 3) / 4, 256, 0, stream>>>(rowptr, col, dis, h1bf, b1, agg1, N);

    // layer 2 (gemm reads f32 agg1, writes dis-prescaled bf16 h2')
    gemm_mfma<64><<<gblocks, 256, 0, stream>>>(agg1, w2h, w2l, dis, h2bf, N, 128);
    agg_gather<64><<<(N + 7) / 8, 256, 0, stream>>>(rowptr, col, dis, h2bf, b2, agg2, N);

    // pool + head
    pool_kernel<<<(N + 127) / 128, 256, 0, stream>>>(agg2, batch, pooled, cnt, N);
    final_kernel<<<1, 256, 0, stream>>>(pooled, cnt, Wlin, blin, out);
}

// Round 14
// 274.454 us; speedup vs baseline: 2.9161x; 1.0286x over previous
//
#include <hip/hip_runtime.h>

// GCN 2-layer + mean-pool + linear head, f32.
// Round 14: pipeline the GEMM (was stall-bound: MfmaUtil 10%, VALU 12%,
// 700 GB/s — latency + 2 barriers per K-step on the critical path).
//   - double-buffered A LDS -> ONE barrier per K-step
//   - next-tile A loads + next-step B fragment loads issued after the
//     barrier, BEFORE the MFMA block (latency hides under 48 MFMAs);
//     convert + ds_write into buf^1 after the MFMAs.
//   - K is a template param -> fully unrolled, prefetch regs are SSA.
// CSR build (bucketed counting sort), bf16 agg_gather, pool unchanged.

#define NN 100000
#define NG 128
#define BNODES 256
#define NBUK ((NN + BNODES - 1) / BNODES)   // 391
#define BCAP 6144

typedef __attribute__((ext_vector_type(8))) short short8;
typedef __attribute__((ext_vector_type(8))) unsigned short u16x8;
typedef __attribute__((ext_vector_type(4))) float f32x4;

__device__ __forceinline__ unsigned short f2bf(float f) {
    union { float f; unsigned u; } v; v.f = f;
    unsigned r = v.u + 0x7fffu + ((v.u >> 16) & 1u);  // round-nearest-even
    return (unsigned short)(r >> 16);
}
__device__ __forceinline__ float bf2f(unsigned short h) {
    union { unsigned u; float f; } v; v.u = ((unsigned)h) << 16;
    return v.f;
}

// ---- pass 1: bucket edges by dst>>8 with privatized histograms ----
__global__ __launch_bounds__(256) void bucket_scatter(const int* __restrict__ src,
                                                      const int* __restrict__ dst,
                                                      int* __restrict__ bcnt,
                                                      int2* __restrict__ pairs, int E) {
    __shared__ int hist[NBUK];
    __shared__ int lbase[NBUK];
    __shared__ int lfill[NBUK];
    const int t = threadIdx.x;
    const int chunk = (E + gridDim.x - 1) / gridDim.x;
    const int lo = blockIdx.x * chunk;
    const int hi = min(E, lo + chunk);
    for (int b = t; b < NBUK; b += 256) { hist[b] = 0; lfill[b] = 0; }
    __syncthreads();
    for (int i = lo + t; i < hi; i += 256)
        atomicAdd(&hist[dst[i] >> 8], 1);
    __syncthreads();
    for (int b = t; b < NBUK; b += 256)
        lbase[b] = hist[b] ? atomicAdd(&bcnt[b], hist[b]) : 0;
    __syncthreads();
    for (int i = lo + t; i < hi; i += 256) {
        const int s = src[i], d = dst[i];
        const int b = d >> 8;
        const int off = atomicAdd(&lfill[b], 1);
        pairs[(size_t)b * BCAP + lbase[b] + off] = make_int2(s, d);
    }
}

// ---- pass 2a: exclusive scan of bucket counts -> bucket bases ----
__global__ __launch_bounds__(512) void bucket_scan(const int* __restrict__ bcnt,
                                                   int* __restrict__ bbase,
                                                   int* __restrict__ rowptr,
                                                   int N, int E) {
    __shared__ int sm[512];
    const int t = threadIdx.x;
    sm[t] = (t < NBUK) ? bcnt[t] : 0;
    __syncthreads();
    for (int d = 1; d < 512; d <<= 1) {
        int a = (t >= d) ? sm[t - d] : 0;
        __syncthreads();
        sm[t] += a;
        __syncthreads();
    }
    if (t <= NBUK) bbase[t] = (t == 0) ? 0 : sm[t - 1];
    if (t == 0) rowptr[N] = E;
}

// ---- pass 2b: per-bucket node histogram + scan -> rowptr/dis, col fill ----
__global__ __launch_bounds__(256) void bucket_build(const int2* __restrict__ pairs,
                                                    const int* __restrict__ bcnt,
                                                    const int* __restrict__ bbase,
                                                    int* __restrict__ rowptr,
                                                    float* __restrict__ dis,
                                                    int* __restrict__ col, int N) {
    __shared__ int cnt[BNODES];
    __shared__ int sm[BNODES];
    __shared__ int pref[BNODES];
    __shared__ int fillc[BNODES];
    const int b = blockIdx.x;
    const int t = threadIdx.x;
    const int nbase = b * BNODES;
    const int ecnt = bcnt[b];
    const int2* ep = pairs + (size_t)b * BCAP;
    const int gbase = bbase[b];

    cnt[t] = 0;
    fillc[t] = 0;
    __syncthreads();
    for (int i = t; i < ecnt; i += 256)
        atomicAdd(&cnt[ep[i].y & (BNODES - 1)], 1);
    __syncthreads();
    sm[t] = cnt[t];
    __syncthreads();
    for (int d = 1; d < 256; d <<= 1) {
        int a = (t >= d) ? sm[t - d] : 0;
        __syncthreads();
        sm[t] += a;
        __syncthreads();
    }
    pref[t] = sm[t] - cnt[t];
    const int node = nbase + t;
    if (node < N) {
        rowptr[node] = gbase + pref[t];
        dis[node] = rsqrtf((float)cnt[t] + 1.0f);
    }
    __syncthreads();
    for (int i = t; i < ecnt; i += 256) {
        const int2 e = ep[i];
        const int d = e.y & (BNODES - 1);
        const int pos = gbase + pref[d] + atomicAdd(&fillc[d], 1);
        col[pos] = e.x;
    }
}

// One-time weight pack: W [K][BN] f32 -> hi/lo bf16 in MFMA fragment order.
__global__ __launch_bounds__(256) void pack_w(const float* __restrict__ W,
                                              unsigned short* __restrict__ packH,
                                              unsigned short* __restrict__ packL,
                                              int K, int BN) {
    const int idx = blockIdx.x * blockDim.x + threadIdx.x;
    if (idx >= K * BN) return;
    const int e = idx & 7;
    const int l = (idx >> 3) & 63;
    const int rest = idx >> 9;  // ks*NF + nf
    const int NF = BN >> 4;
    const int nf = rest % NF;
    const int ks = rest / NF;
    const int n = nf * 16 + (l & 15);
    const int k = ks * 32 + ((l >> 4) & 3) * 8 + e;
    const float v = W[(size_t)k * BN + n];
    const unsigned short h = f2bf(v);
    packH[idx] = h;
    packL[idx] = f2bf(v - bf2f(h));
}

// MFMA split-bf16 GEMM, double-buffered single-barrier pipeline.
// A [N][K] f32 row-major, W pre-packed fragments, Out bf16 (dis-prescaled).
template <int BN, int K>
__global__ __launch_bounds__(256) void gemm_mfma(const float* __restrict__ A,
                                                 const unsigned short* __restrict__ WpH,
                                                 const unsigned short* __restrict__ WpL,
                                                 const float* __restrict__ scale,
                                                 unsigned short* __restrict__ Out,
                                                 int N) {
    constexpr int BM = 128;
    constexpr int NK = K / 32;
    constexpr int WROWS = (BN == 128) ? 2 : 4;
    constexpr int WCOLS = (BN == 128) ? 2 : 1;
    constexpr int WTM = BM / WROWS;
    constexpr int MF = WTM / 16;
    constexpr int NFW = (BN / WCOLS) / 16;
    constexpr int NFB = BN / 16;

    __shared__ unsigned short AsH[2][8][512];
    __shared__ unsigned short AsL[2][8][512];

    const int t = threadIdx.x;
    const int wid = t >> 6, lane = t & 63;
    const int wr = wid / WCOLS, wc = wid % WCOLS;
    const int r0 = blockIdx.x * BM;

    const int s_row1 = t >> 2;         // 0..63,  m = wid
    const int s_row2 = 64 + (t >> 2);  // 64..127, m = 4 + wid
    const int s_kg = t & 3;
    const int s_lf = ((t >> 2) & 15) + s_kg * 16;  // bijective per wave

    const bool ok1 = (r0 + s_row1) < N;
    const bool ok2 = (r0 + s_row2) < N;
    const float* aptr1 = A + (size_t)(r0 + s_row1) * K + s_kg * 8;
    const float* aptr2 = A + (size_t)(r0 + s_row2) * K + s_kg * 8;

    auto loadA = [&](int ks, float4* v) {
        v[0] = v[1] = v[2] = v[3] = make_float4(0.f, 0.f, 0.f, 0.f);
        if (ok1) {
            v[0] = *(const float4*)(aptr1 + ks * 32);
            v[1] = *(const float4*)(aptr1 + ks * 32 + 4);
        }
        if (ok2) {
            v[2] = *(const float4*)(aptr2 + ks * 32);
            v[3] = *(const float4*)(aptr2 + ks * 32 + 4);
        }
    };
    auto cvtwrite = [&](int buf, const float4* v) {
#pragma unroll
        for (int uu = 0; uu < 2; ++uu) {
            short8 h, l;
            const float vv[8] = {v[2 * uu].x,     v[2 * uu].y,
                                 v[2 * uu].z,     v[2 * uu].w,
                                 v[2 * uu + 1].x, v[2 * uu + 1].y,
                                 v[2 * uu + 1].z, v[2 * uu + 1].w};
#pragma unroll
            for (int j = 0; j < 8; ++j) {
                const unsigned short hh = f2bf(vv[j]);
                h[j] = (short)hh;
                l[j] = (short)f2bf(vv[j] - bf2f(hh));
            }
            const int m = uu ? (4 + wid) : wid;
            *(short8*)&AsH[buf][m][s_lf * 8] = h;
            *(short8*)&AsL[buf][m][s_lf * 8] = l;
        }
    };
    auto loadB = [&](int ks, short8* bH, short8* bL) {
#pragma unroll
        for (int n = 0; n < NFW; ++n) {
            const int nfg = wc * NFW + n;
            const int base = ((ks * NFB + nfg) * 64 + lane) * 8;
            bH[n] = *(const short8*)&WpH[base];
            bL[n] = *(const short8*)&WpL[base];
        }
    };

    f32x4 acc[MF][NFW];
#pragma unroll
    for (int m = 0; m < MF; ++m)
#pragma unroll
        for (int n = 0; n < NFW; ++n) acc[m][n] = (f32x4){0.f, 0.f, 0.f, 0.f};

    // prologue: tile 0 staged, B fragments for step 0 in registers
    float4 av[4];
    loadA(0, av);
    cvtwrite(0, av);
    short8 bHc[NFW], bLc[NFW];
    loadB(0, bHc, bLc);

#pragma unroll
    for (int ks = 0; ks < NK; ++ks) {
        const int cur = ks & 1;
        __syncthreads();  // buf[cur] ready; previous readers done
        // issue next-step prefetches (latency hides under MFMAs below)
        float4 avn[4];
        short8 bHn[NFW], bLn[NFW];
        if (ks + 1 < NK) {
            loadA(ks + 1, avn);
            loadB(ks + 1, bHn, bLn);
        }
        // consume buf[cur]
#pragma unroll
        for (int m = 0; m < MF; ++m) {
            const int mf = wr * MF + m;
            const short8 aH = *(const short8*)&AsH[cur][mf][lane * 8];
            const short8 aL = *(const short8*)&AsL[cur][mf][lane * 8];
#pragma unroll
            for (int n = 0; n < NFW; ++n) {
                acc[m][n] = __builtin_amdgcn_mfma_f32_16x16x32_bf16(aH, bHc[n], acc[m][n], 0, 0, 0);
                acc[m][n] = __builtin_amdgcn_mfma_f32_16x16x32_bf16(aH, bLc[n], acc[m][n], 0, 0, 0);
                acc[m][n] = __builtin_amdgcn_mfma_f32_16x16x32_bf16(aL, bHc[n], acc[m][n], 0, 0, 0);
            }
        }
        // stage next tile into the other buffer; rotate B registers
        if (ks + 1 < NK) {
            cvtwrite(cur ^ 1, avn);
#pragma unroll
            for (int n = 0; n < NFW; ++n) {
                bHc[n] = bHn[n];
                bLc[n] = bLn[n];
            }
        }
    }

    // epilogue: C write, bf16(scale[row] * acc)
#pragma unroll
    for (int m = 0; m < MF; ++m) {
        const int row0 = r0 + wr * WTM + m * 16 + ((lane >> 4) << 2);
        float sc[4];
#pragma unroll
        for (int r = 0; r < 4; ++r) sc[r] = (row0 + r < N) ? scale[row0 + r] : 0.f;
#pragma unroll
        for (int n = 0; n < NFW; ++n) {
            const int cn = wc * (NFW * 16) + n * 16 + (lane & 15);
#pragma unroll
            for (int r = 0; r < 4; ++r) {
                if (row0 + r < N)
                    Out[(size_t)(row0 + r) * BN + cn] = f2bf(acc[m][n][r] * sc[r]);
            }
        }
    }
}

// CSR gather aggregation over PRE-SCALED bf16 H' (= bf16(dis*h)).
// 8 cols/lane (16B bf16x8). COLS=128: 1 node/wave, 4 subgroups x 16 lanes.
// COLS=64: 2 nodes/wave, 4 subgroups x 8 lanes each. Uniform trip count
// ceil(remain/4); out-of-range masked by VALUE (weight 0, safe row node).
// Out[d] = relu( dis[d] * (sum_s H'[s] + H'[d]) + bias )   [f32 output]
template <int COLS>
__global__ __launch_bounds__(256) void agg_gather(const int* __restrict__ rowptr,
                                                  const int* __restrict__ col,
                                                  const float* __restrict__ dis,
                                                  const unsigned short* __restrict__ Hs,
                                                  const float* __restrict__ bias,
                                                  float* __restrict__ Out, int N) {
    constexpr int NPW = (COLS == 128) ? 1 : 2;  // nodes per wave
    constexpr int LPN = 64 / NPW;               // lanes per node group
    constexpr int LPR = COLS / 8;               // lanes per row (bf16x8)
    constexpr int NSG = LPN / LPR;              // 4 edge subgroups
    const int gw = (int)((blockIdx.x * blockDim.x + threadIdx.x) >> 6);
    const int lane = threadIdx.x & 63;
    const int sub = lane / LPN;    // node within wave
    const int nl = lane % LPN;     // lane within node group
    const int esub = nl / LPR;     // edge subgroup 0..3
    const int sl = nl % LPR;       // 8-col group within row
    const int node = gw * NPW + sub;
    const int lgbase = sub * LPN;

    float acc[8];
#pragma unroll
    for (int k = 0; k < 8; ++k) acc[k] = 0.f;

    int base = 0, len = 0;
    const int nodec = (node < N) ? node : 0;
    if (node < N) {
        base = rowptr[node];
        len = rowptr[node + 1] - base;
    }

    for (int j0 = 0; j0 < len; j0 += LPN) {
        const int remain = min(LPN, len - j0);
        const int sidx = (nl < remain) ? col[base + j0 + nl] : nodec;
        const int qtr = (remain + NSG - 1) / NSG;  // uniform trip count
        const int off = esub * qtr;
        int u = 0;
        for (; u + 8 <= qtr; u += 8) {
            u16x8 hv[8];
            float wv[8];
#pragma unroll
            for (int b = 0; b < 8; ++b) {
                const int idx = off + u + b;
                const int s = __shfl(sidx, lgbase + idx);
                wv[b] = (idx < remain) ? 1.f : 0.f;
                hv[b] = *(const u16x8*)(Hs + (size_t)s * COLS + sl * 8);
            }
#pragma unroll
            for (int b = 0; b < 8; ++b)
#pragma unroll
                for (int k = 0; k < 8; ++k)
                    acc[k] = fmaf(bf2f(hv[b][k]), wv[b], acc[k]);
        }
        for (; u + 4 <= qtr; u += 4) {
            u16x8 hv[4];
            float wv[4];
#pragma unroll
            for (int b = 0; b < 4; ++b) {
                const int idx = off + u + b;
                const int s = __shfl(sidx, lgbase + idx);
                wv[b] = (idx < remain) ? 1.f : 0.f;
                hv[b] = *(const u16x8*)(Hs + (size_t)s * COLS + sl * 8);
            }
#pragma unroll
            for (int b = 0; b < 4; ++b)
#pragma unroll
                for (int k = 0; k < 8; ++k)
                    acc[k] = fmaf(bf2f(hv[b][k]), wv[b], acc[k]);
        }
        for (; u < qtr; ++u) {
            const int idx = off + u;
            const int s = __shfl(sidx, lgbase + idx);
            const float w = (idx < remain) ? 1.f : 0.f;
            const u16x8 hv = *(const u16x8*)(Hs + (size_t)s * COLS + sl * 8);
#pragma unroll
            for (int k = 0; k < 8; ++k)
                acc[k] = fmaf(bf2f(hv[k]), w, acc[k]);
        }
    }

#pragma unroll
    for (int k = 0; k < 8; ++k) {
        acc[k] += __shfl_xor(acc[k], LPR);
        acc[k] += __shfl_xor(acc[k], 2 * LPR);
    }

    if (node < N && esub == 0) {
        const float dd = dis[node];
        const u16x8 hsb = *(const u16x8*)(Hs + (size_t)node * COLS + sl * 8);
        const f32x4 bv0 = *(const f32x4*)(bias + sl * 8);
        const f32x4 bv1 = *(const f32x4*)(bias + sl * 8 + 4);
        f32x4 o0, o1;
#pragma unroll
        for (int k = 0; k < 4; ++k) {
            o0[k] = fmaxf(fmaf(acc[k] + bf2f(hsb[k]), dd, bv0[k]), 0.f);
            o1[k] = fmaxf(fmaf(acc[k + 4] + bf2f(hsb[k + 4]), dd, bv1[k]), 0.f);
        }
        *(f32x4*)(Out + (size_t)node * COLS + sl * 8) = o0;
        *(f32x4*)(Out + (size_t)node * COLS + sl * 8 + 4) = o1;
    }
}

// mean-pool prep: wave = 32 consecutive rows, lane = column.
__global__ __launch_bounds__(256) void pool_kernel(const float* __restrict__ H,
                                                   const int* __restrict__ batch,
                                                   float* __restrict__ pooled,
                                                   float* __restrict__ cnt, int N) {
    const int c = threadIdx.x & 63;
    const int w = threadIdx.x >> 6;          // wave 0..3
    const int row0 = blockIdx.x * 128 + w * 32;
    if (row0 >= N) return;
    const int nr = min(32, N - row0);

    float v[32];
    int b[32];
#pragma unroll
    for (int i = 0; i < 32; ++i) {
        const int r = row0 + i;
        if (i < nr) {
            v[i] = H[(size_t)r * 64 + c];
            b[i] = batch[r];
        } else {
            v[i] = 0.f;
            b[i] = -1;
        }
    }
    int cur = b[0];
    float sum = 0.f, csum = 0.f;
#pragma unroll
    for (int i = 0; i < 32; ++i) {
        if (i < nr) {
            if (b[i] != cur) {
                atomicAdd(&pooled[cur * 64 + c], sum);
                if (c == 0) atomicAdd(&cnt[cur], csum);
                cur = b[i];
                sum = 0.f;
                csum = 0.f;
            }
            sum += v[i];
            csum += 1.f;
        }
    }
    atomicAdd(&pooled[cur * 64 + c], sum);
    if (c == 0) atomicAdd(&cnt[cur], csum);
}

__global__ __launch_bounds__(256) void final_kernel(const float* __restrict__ pooled,
                                                    const float* __restrict__ cnt,
                                                    const float* __restrict__ Wlin,
                                                    const float* __restrict__ blin,
                                                    float* __restrict__ out) {
    const int t = threadIdx.x;
    const int g = t >> 1, o = t & 1;
    const float inv = 1.0f / fmaxf(cnt[g], 1.0f);
    float s = 0.f;
#pragma unroll
    for (int j = 0; j < 64; ++j) s = fmaf(pooled[g * 64 + j], Wlin[j * 2 + o], s);
    out[t] = s * inv + blin[o];
}

extern "C" void kernel_launch(void* const* d_in, const int* in_sizes, int n_in,
                              void* d_out, int out_size, void* d_ws, size_t ws_size,
                              hipStream_t stream) {
    const float* x     = (const float*)d_in[0];
    const int*   edge  = (const int*)d_in[1];
    const int*   batch = (const int*)d_in[2];
    const float* W1    = (const float*)d_in[3];
    const float* b1    = (const float*)d_in[4];
    const float* W2    = (const float*)d_in[5];
    const float* b2    = (const float*)d_in[6];
    const float* Wlin  = (const float*)d_in[7];
    const float* blin  = (const float*)d_in[8];
    float* out = (float*)d_out;

    const int N = NN;
    const int E = in_sizes[1] / 2;
    const int* src = edge;
    const int* dst = edge + E;

    char* ws = (char*)d_ws;
    size_t off = 0;
    auto alloc = [&](size_t bytes) -> void* {
        void* p = ws + off;
        off += (bytes + 511) & ~(size_t)511;
        return p;
    };
    float* dis    = (float*)alloc((size_t)N * 4);
    int*   rowptr = (int*)alloc((size_t)(N + 1) * 4);
    int*   bcnt   = (int*)alloc((size_t)NBUK * 4);
    int*   bbase  = (int*)alloc((size_t)(NBUK + 1) * 4);
    int*   col    = (int*)alloc((size_t)E * 4);                 // 6.4 MB
    int2*  pairs  = (int2*)alloc((size_t)NBUK * BCAP * 8);      // 19.2 MB
    unsigned short* w1h = (unsigned short*)alloc((size_t)384 * 128 * 2);
    unsigned short* w1l = (unsigned short*)alloc((size_t)384 * 128 * 2);
    unsigned short* w2h = (unsigned short*)alloc((size_t)128 * 64 * 2);
    unsigned short* w2l = (unsigned short*)alloc((size_t)128 * 64 * 2);
    unsigned short* h1bf = (unsigned short*)alloc((size_t)N * 128 * 2);  // 25.6 MB
    float* agg1   = (float*)alloc((size_t)N * 128 * 4);                  // 51.2 MB
    float* pooled = (float*)alloc((size_t)NG * 64 * 4);
    float* cnt    = (float*)alloc((size_t)NG * 4);
    unsigned short* h2bf = h1bf;   // layer-2 reuse (h1bf dead after agg<128>)
    float* agg2 = agg1;            // agg1 dead after gemm2 reads it

    hipMemsetAsync(bcnt, 0, (size_t)NBUK * 4, stream);
    hipMemsetAsync(pooled, 0, (size_t)NG * 64 * 4, stream);
    hipMemsetAsync(cnt, 0, (size_t)NG * 4, stream);

    // weight packing (tiny, once per call)
    pack_w<<<(384 * 128 + 255) / 256, 256, 0, stream>>>(W1, w1h, w1l, 384, 128);
    pack_w<<<(128 * 64 + 255) / 256, 256, 0, stream>>>(W2, w2h, w2l, 128, 64);

    // CSR build via bucketed counting sort (no global random atomics)
    bucket_scatter<<<512, 256, 0, stream>>>(src, dst, bcnt, pairs, E);
    bucket_scan<<<1, 512, 0, stream>>>(bcnt, bbase, rowptr, N, E);
    bucket_build<<<NBUK, 256, 0, stream>>>(pairs, bcnt, bbase, rowptr, dis, col, N);

    const int gblocks = (N + 127) / 128;
    // layer 1 (gemm writes dis-prescaled bf16 h1')
    gemm_mfma<128, 384><<<gblocks, 256, 0, stream>>>(x, w1h, w1l, dis, h1bf, N);
    agg_gather<128><<<(N + 3) / 4, 256, 0, stream>>>(rowptr, col, dis, h1bf, b1, agg1, N);

    // layer 2 (gemm reads f32 agg1, writes dis-prescaled bf16 h2')
    gemm_mfma<64, 128><<<gblocks, 256, 0, stream>>>(agg1, w2h, w2l, dis, h2bf, N);
    agg_gather<64><<<(N + 7) / 8, 256, 0, stream>>>(rowptr, col, dis, h2bf, b2, agg2, N);

    // pool + head
    pool_kernel<<<(N + 127) / 128, 256, 0, stream>>>(agg2, batch, pooled, cnt, N);
    final_kernel<<<1, 256, 0, stream>>>(pooled, cnt, Wlin, blin, out);
}